// Round 4
// baseline (3614.577 us; speedup 1.0000x reference)
//
#include <hip/hip_runtime.h>
#include <hip/hip_bf16.h>
#include <math.h>

// Problem constants
#define ROWS 256000     // B*S = 512*500
#define BATCH 512

// prep region (float offsets in ws, always f32)
#define OFF_TK   0          // tk [50][50]
#define OFF_WVT  2512       // WvT [4000][200]
#define OFF_WT   802512     // WT  [200][400]  (We.T | Wa.T)
#define OFF_W1T  882512     // W1T [250][128]  (zero-padded u>=100)
#define OFF_W2T  914512     // W2T [100][52]   (zero-padded f>=50)
#define PREP_FLOATS 919712

// output layout (float offsets)
#define OUT_MAST 12800000
#define OUT_LOG  13056000
#define OUT_PROB 14080000

// storage-type helpers (big intermediate arrays may be f32 or bf16)
__device__ inline float ldT(const float* p) { return *p; }
__device__ inline float ldT(const __hip_bfloat16* p) { return __bfloat162float(*p); }
__device__ inline void stT(float* p, float v) { *p = v; }
__device__ inline void stT(__hip_bfloat16* p, float v) { *p = __float2bfloat16(v); }

// ---------------------------------------------------------------- prep ----
__global__ __launch_bounds__(256) void prep_kernel(
    const float* __restrict__ keymem, const float* __restrict__ Wk,
    const float* __restrict__ bk, const float* __restrict__ Wv,
    const float* __restrict__ We, const float* __restrict__ Wa,
    const float* __restrict__ W1, const float* __restrict__ W2,
    float* __restrict__ ws) {
  int idx = blockIdx.x * 256 + threadIdx.x;
  if (idx < 2500) {                      // tk[m][k] = sum_l km[l][k]*Wk[m][l] + bk[m]
    int m = idx / 50, k = idx - m * 50;
    float acc = bk[m];
    for (int l = 0; l < 50; ++l) acc = fmaf(keymem[l*50 + k], Wk[m*50 + l], acc);
    ws[OFF_TK + m*50 + k] = acc;
    return;
  }
  idx -= 2500;
  if (idx < 800000) {                    // WvT[j][v] = Wv[v][j]
    int j = idx / 200, v = idx - j * 200;
    ws[OFF_WVT + j*200 + v] = Wv[v*4000 + j];
    return;
  }
  idx -= 800000;
  if (idx < 80000) {                     // WT[v][c]
    int v = idx / 400, c = idx - v * 400;
    ws[OFF_WT + v*400 + c] = (c < 200) ? We[c*200 + v] : Wa[(c-200)*200 + v];
    return;
  }
  idx -= 80000;
  if (idx < 32000) {                     // W1T[j][u], [250][128]
    int j = idx / 128, u = idx - j * 128;
    ws[OFF_W1T + j*128 + u] = (u < 100) ? W1[u*250 + j] : 0.f;
    return;
  }
  idx -= 32000;
  if (idx < 5200) {                      // W2T[j][f], [100][52]
    int j = idx / 52, f = idx - j * 52;
    ws[OFF_W2T + j*52 + f] = (f < 50) ? W2[f*100 + j] : 0.f;
    return;
  }
}

// ---------------------------------------------------------------- attn ----
// wave per (b,t) row; 4 waves per block; attn buffer is chunk-local
template <typename T>
__global__ __launch_bounds__(256) void attn_kernel(
    const int* __restrict__ questions, const float* __restrict__ qtab,
    const float* __restrict__ Wq, const float* __restrict__ bq,
    const float* __restrict__ ws, T* __restrict__ attn, int row0) {
  __shared__ float qe_s[4][52];
  __shared__ float qu_s[4][52];
  int w = threadIdx.x >> 6;
  int lane = threadIdx.x & 63;
  int lrow = blockIdx.x * 4 + w;
  int row = row0 + lrow;
  int qi = questions[row];
  if (lane < 50) qe_s[w][lane] = qtab[qi*50 + lane];
  __syncthreads();
  if (lane < 50) {
    float acc = bq[lane];
    const float* wq = Wq + lane*50;
    #pragma unroll
    for (int j = 0; j < 50; ++j) acc = fmaf(qe_s[w][j], wq[j], acc);
    qu_s[w][lane] = tanhf(acc);
  }
  __syncthreads();
  float sc = -3.0e38f;
  if (lane < 50) {
    float acc = 0.f;
    const float* tkr = ws + OFF_TK + lane*50;
    #pragma unroll
    for (int k = 0; k < 50; ++k) acc = fmaf(qu_s[w][k], tkr[k], acc);
    sc = acc;
  }
  float mx = sc;
  #pragma unroll
  for (int d = 32; d > 0; d >>= 1) mx = fmaxf(mx, __shfl_xor(mx, d));
  float ex = (lane < 50) ? __expf(sc - mx) : 0.f;
  float sm = ex;
  #pragma unroll
  for (int d = 32; d > 0; d >>= 1) sm += __shfl_xor(sm, d);
  if (lane < 50) stT(&attn[lrow*50 + lane], ex / sm);
}

// ------------------------------------------------------------ erase/add ----
// 32 rows per block; C[32 x 400] = VE[32 x 200] @ WT[200 x 400]; er/ad chunk-local
template <typename T>
__global__ __launch_bounds__(256) void ea_kernel(
    const int* __restrict__ questions, const int* __restrict__ responses,
    const float* __restrict__ bv, const float* __restrict__ be,
    const float* __restrict__ ba, const float* __restrict__ ws,
    T* __restrict__ er, T* __restrict__ ad, int row0) {
  __shared__ float ve_s[32][200];
  int tid = threadIdx.x;
  int lrow0 = blockIdx.x * 32;
  const float* wvt = ws + OFF_WVT;
  for (int i = tid; i < 6400; i += 256) {
    int r = i / 200, v = i - r * 200;
    int row = row0 + lrow0 + r;
    int qi = questions[row];
    float acc = bv[v];
    if (qi > 0) {
      int resp = responses[row];
      const float* base = wvt + (qi - 1) * 200 + v;
      #pragma unroll
      for (int c = 0; c < 4; ++c) {
        float wgt = 1.f - fabsf((float)(c - resp)) * (1.f / 3.f);
        if (wgt > 0.f) acc = fmaf(wgt, base[c * 200000], acc);
      }
    }
    ve_s[r][v] = acc;
  }
  __syncthreads();
  const float* wt = ws + OFF_WT;
  float acc0[32], acc1[32];
  #pragma unroll
  for (int r = 0; r < 32; ++r) { acc0[r] = 0.f; acc1[r] = 0.f; }
  int c0 = tid, c1 = tid + 256;
  bool has1 = (c1 < 400);
  for (int v = 0; v < 200; ++v) {
    float w0 = wt[v*400 + c0];
    float w1 = has1 ? wt[v*400 + c1] : 0.f;
    #pragma unroll
    for (int r = 0; r < 32; ++r) {
      float h = ve_s[r][v];
      acc0[r] = fmaf(h, w0, acc0[r]);
      acc1[r] = fmaf(h, w1, acc1[r]);
    }
  }
  if (c0 < 200) {
    float bias = be[c0];
    #pragma unroll
    for (int r = 0; r < 32; ++r) {
      float x = acc0[r] + bias;
      stT(&er[(lrow0 + r)*200 + c0], 1.f / (1.f + __expf(-x)));
    }
  } else {
    float bias = ba[c0 - 200];
    #pragma unroll
    for (int r = 0; r < 32; ++r)
      stT(&ad[(lrow0 + r)*200 + (c0 - 200)], tanhf(acc0[r] + bias));
  }
  if (has1) {
    float bias = ba[c1 - 200];
    #pragma unroll
    for (int r = 0; r < 32; ++r)
      stT(&ad[(lrow0 + r)*200 + (c1 - 200)], tanhf(acc1[r] + bias));
  }
}

// ------------------------------------------------------------ recurrence ----
// block per (chunk-local) batch element; thread v<200 owns Vm[:, v] in 50 regs.
// All buffers chunk-local; ivm is shared across batch.
template <typename T>
__global__ __launch_bounds__(256) void rec_kernel(
    const float* __restrict__ ivm, const T* __restrict__ attn,
    const T* __restrict__ er, const T* __restrict__ ad,
    T* __restrict__ rd) {
  __shared__ float att_s[2][64];
  int tid = threadIdx.x;
  int base = blockIdx.x * 500;
  float vm[50];
  float e_c = 0.f, a_c = 0.f;
  if (tid < 200) {
    #pragma unroll
    for (int m = 0; m < 50; ++m) vm[m] = ivm[m*200 + tid];
    e_c = ldT(&er[base*200 + tid]);
    a_c = ldT(&ad[base*200 + tid]);
  } else if (tid < 250) {
    att_s[0][tid - 200] = ldT(&attn[base*50 + (tid - 200)]);
  }
  __syncthreads();
  for (int t = 0; t < 500; ++t) {
    int pb = t & 1;
    float e_n = 0.f, a_n = 0.f, at_n = 0.f;
    if (t < 499) {
      int rn = base + t + 1;
      if (tid < 200) { e_n = ldT(&er[rn*200 + tid]); a_n = ldT(&ad[rn*200 + tid]); }
      else if (tid < 250) at_n = ldT(&attn[rn*50 + (tid - 200)]);
    }
    if (tid < 200) {
      float r0 = 0.f, r1 = 0.f;
      #pragma unroll
      for (int m = 0; m < 50; m += 2) {
        float a0 = att_s[pb][m];
        float a1 = att_s[pb][m + 1];
        r0 = fmaf(a0, vm[m], r0);
        r1 = fmaf(a1, vm[m + 1], r1);
        float t0 = fmaf(-vm[m],     e_c, a_c);   // add - vm*erase
        float t1 = fmaf(-vm[m + 1], e_c, a_c);
        vm[m]     = fmaf(a0, t0, vm[m]);
        vm[m + 1] = fmaf(a1, t1, vm[m + 1]);
      }
      stT(&rd[(base + t)*200 + tid], r0 + r1);
    }
    if (t < 499) {
      if (tid < 200) { e_c = e_n; a_c = a_n; }
      else if (tid < 250) att_s[pb ^ 1][tid - 200] = at_n;
    }
    __syncthreads();
  }
}

// ---------------------------------------------------------------- MLP ----
// 64 rows/block, 512 threads; GEMM1 [64x128] K=250 (4x4 reg tile), GEMM2 [64x52] K=100
#define W1S 0
#define HS  6400
#define Z1S 0
#define W2S 6656
#define FTS 11856

template <typename T>
__global__ __launch_bounds__(512) void mlp_kernel(
    const int* __restrict__ questions, const float* __restrict__ qtab,
    const float* __restrict__ b1, const float* __restrict__ b2,
    const float* __restrict__ Wo, const float* __restrict__ bo,
    const float* __restrict__ ws, const T* __restrict__ rd,
    float* __restrict__ out, int row0) {
  __shared__ __align__(16) float smem[15184];
  int tid = threadIdx.x;
  int lrow0 = blockIdx.x * 64;
  const float* w1t = ws + OFF_W1T;
  int ug = tid & 31, rg = tid >> 5;
  int u0 = ug * 4, r0 = rg * 4;
  float acc[4][4];
  #pragma unroll
  for (int i = 0; i < 4; ++i)
    #pragma unroll
    for (int j = 0; j < 4; ++j) acc[i][j] = 0.f;

  for (int kt = 0; kt < 5; ++kt) {
    int j0 = kt * 50;
    for (int i = tid; i < 6400; i += 512)        // W1T tile [50][128]
      smem[W1S + i] = w1t[j0*128 + i];
    for (int i = tid; i < 3200; i += 512) {      // h tile [64][50]
      int r = i / 50, jj = i - r * 50;
      int lrow = lrow0 + r;
      int j = j0 + jj;
      float hv;
      if (j < 200) hv = ldT(&rd[lrow*200 + j]);
      else         hv = qtab[questions[row0 + lrow]*50 + (j - 200)];
      smem[HS + r*50 + jj] = hv;
    }
    __syncthreads();
    #pragma unroll 2
    for (int jj = 0; jj < 50; ++jj) {
      float4 wv = *(const float4*)&smem[W1S + jj*128 + u0];
      #pragma unroll
      for (int rr = 0; rr < 4; ++rr) {
        float h = smem[HS + (r0 + rr)*50 + jj];
        acc[rr][0] = fmaf(h, wv.x, acc[rr][0]);
        acc[rr][1] = fmaf(h, wv.y, acc[rr][1]);
        acc[rr][2] = fmaf(h, wv.z, acc[rr][2]);
        acc[rr][3] = fmaf(h, wv.w, acc[rr][3]);
      }
    }
    __syncthreads();
  }
  // z1 = relu(acc + b1) into LDS [64][104]
  if (u0 < 100) {
    #pragma unroll
    for (int uu = 0; uu < 4; ++uu) {
      int u = u0 + uu;
      float bb = b1[u];
      #pragma unroll
      for (int rr = 0; rr < 4; ++rr) {
        float z = acc[rr][uu] + bb;
        smem[Z1S + (r0 + rr)*104 + u] = fmaxf(z, 0.f);
      }
    }
  }
  for (int i = tid; i < 5200; i += 512)          // W2T [100][52]
    smem[W2S + i] = ws[OFF_W2T + i];
  __syncthreads();
  // GEMM2: feat [64][50]
  for (int i = tid; i < 832; i += 512) {
    int r = i / 13, fg = i - r * 13;
    int f0 = fg * 4;
    float a0 = 0.f, a1 = 0.f, a2 = 0.f, a3 = 0.f;
    #pragma unroll 4
    for (int j = 0; j < 100; ++j) {
      float z = smem[Z1S + r*104 + j];
      float4 wv = *(const float4*)&smem[W2S + j*52 + f0];
      a0 = fmaf(z, wv.x, a0);
      a1 = fmaf(z, wv.y, a1);
      a2 = fmaf(z, wv.z, a2);
      a3 = fmaf(z, wv.w, a3);
    }
    int row = row0 + lrow0 + r;
    float vals[4] = {a0, a1, a2, a3};
    #pragma unroll
    for (int ff = 0; ff < 4; ++ff) {
      int f = f0 + ff;
      if (f < 50) {
        float val = vals[ff] + b2[f];
        smem[FTS + r*52 + f] = val;
        out[row*50 + f] = val;
      }
    }
  }
  __syncthreads();
  // mastery / logits / probs
  if (tid < 64) {
    int r = tid, row = row0 + lrow0 + r;
    float s = 0.f;
    float lg[4] = {bo[0], bo[1], bo[2], bo[3]};
    #pragma unroll
    for (int f = 0; f < 50; ++f) {
      float ft = smem[FTS + r*52 + f];
      s += ft;
      #pragma unroll
      for (int c = 0; c < 4; ++c) lg[c] = fmaf(Wo[c*50 + f], ft, lg[c]);
    }
    out[OUT_MAST + row] = s * (1.f / 50.f);
    float mx = fmaxf(fmaxf(lg[0], lg[1]), fmaxf(lg[2], lg[3]));
    float e0 = __expf(lg[0] - mx), e1 = __expf(lg[1] - mx);
    float e2 = __expf(lg[2] - mx), e3 = __expf(lg[3] - mx);
    float inv = 1.f / (e0 + e1 + e2 + e3);
    #pragma unroll
    for (int c = 0; c < 4; ++c) out[OUT_LOG + row*4 + c] = lg[c];
    out[OUT_PROB + row*4 + 0] = e0 * inv;
    out[OUT_PROB + row*4 + 1] = e1 * inv;
    out[OUT_PROB + row*4 + 2] = e2 * inv;
    out[OUT_PROB + row*4 + 3] = e3 * inv;
  }
}

// ---------------------------------------------------------------- launch ----
// nc = number of batch chunks; scratch holds one chunk's attn/er/ad/rd.
template <typename T>
static void launch_pipeline(const int* questions, const int* responses,
                            const float* qtab, const float* Wv, const float* bv,
                            const float* keymem, const float* ivm,
                            const float* Wq, const float* bq,
                            const float* Wk, const float* bk,
                            const float* We, const float* be,
                            const float* Wa, const float* ba,
                            const float* W1, const float* b1,
                            const float* W2, const float* b2,
                            const float* Wo, const float* bo,
                            float* ws, float* out, int nc, hipStream_t stream) {
  const int RPC = ROWS / nc;          // rows per chunk
  const int BPC = BATCH / nc;         // batch elems per chunk
  T* attn = (T*)((char*)ws + (size_t)PREP_FLOATS * 4);
  T* er   = attn + (size_t)RPC * 50;
  T* ad   = er   + (size_t)RPC * 200;
  T* rd   = ad   + (size_t)RPC * 200;

  prep_kernel<<<3593, 256, 0, stream>>>(keymem, Wk, bk, Wv, We, Wa, W1, W2, ws);
  for (int c = 0; c < nc; ++c) {
    int row0 = c * RPC;
    attn_kernel<T><<<RPC/4,  256, 0, stream>>>(questions, qtab, Wq, bq, ws, attn, row0);
    ea_kernel<T>  <<<RPC/32, 256, 0, stream>>>(questions, responses, bv, be, ba, ws, er, ad, row0);
    rec_kernel<T> <<<BPC,    256, 0, stream>>>(ivm, attn, er, ad, rd);
    mlp_kernel<T> <<<RPC/64, 512, 0, stream>>>(questions, qtab, b1, b2, Wo, bo, ws, rd, out, row0);
  }
}

extern "C" void kernel_launch(void* const* d_in, const int* in_sizes, int n_in,
                              void* d_out, int out_size, void* d_ws, size_t ws_size,
                              hipStream_t stream) {
  const int*   questions = (const int*)d_in[0];
  const int*   responses = (const int*)d_in[1];
  const float* qtab      = (const float*)d_in[2];
  const float* Wv        = (const float*)d_in[3];
  const float* bv        = (const float*)d_in[4];
  const float* keymem    = (const float*)d_in[5];
  const float* ivm       = (const float*)d_in[6];
  const float* Wq        = (const float*)d_in[7];
  const float* bq        = (const float*)d_in[8];
  const float* Wk        = (const float*)d_in[9];
  const float* bk        = (const float*)d_in[10];
  const float* We        = (const float*)d_in[11];
  const float* be        = (const float*)d_in[12];
  const float* Wa        = (const float*)d_in[13];
  const float* ba        = (const float*)d_in[14];
  const float* W1        = (const float*)d_in[15];
  const float* b1        = (const float*)d_in[16];
  const float* W2        = (const float*)d_in[17];
  const float* b2        = (const float*)d_in[18];
  const float* Wo        = (const float*)d_in[19];
  const float* bo        = (const float*)d_in[20];
  float* ws  = (float*)d_ws;
  float* out = (float*)d_out;

  // scratch need: prep + (ROWS/nc) * (50 + 3*200) elements of storage type T
  const size_t prep_b = (size_t)PREP_FLOATS * 4;
  auto need = [&](size_t esz, int nc) {
    return prep_b + ((size_t)ROWS / nc) * 650 * esz;
  };

  if (ws_size >= need(4, 1)) {          // 669 MB: full f32
    launch_pipeline<float>(questions, responses, qtab, Wv, bv, keymem, ivm,
                           Wq, bq, Wk, bk, We, be, Wa, ba, W1, b1, W2, b2,
                           Wo, bo, ws, out, 1, stream);
  } else if (ws_size >= need(2, 1)) {   // 336 MB: full bf16
    launch_pipeline<__hip_bfloat16>(questions, responses, qtab, Wv, bv, keymem, ivm,
                                    Wq, bq, Wk, bk, We, be, Wa, ba, W1, b1, W2, b2,
                                    Wo, bo, ws, out, 1, stream);
  } else if (ws_size >= need(2, 4)) {   // 87 MB: bf16, 4 chunks
    launch_pipeline<__hip_bfloat16>(questions, responses, qtab, Wv, bv, keymem, ivm,
                                    Wq, bq, Wk, bk, We, be, Wa, ba, W1, b1, W2, b2,
                                    Wo, bo, ws, out, 4, stream);
  } else {                              // 24.5 MB: bf16, 16 chunks (last resort)
    launch_pipeline<__hip_bfloat16>(questions, responses, qtab, Wv, bv, keymem, ivm,
                                    Wq, bq, Wk, bk, We, be, Wa, ba, W1, b1, W2, b2,
                                    Wo, bo, ws, out, 16, stream);
  }
}

// Round 6
// 3346.804 us; speedup vs baseline: 1.0800x; 1.0800x over previous
//
#include <hip/hip_runtime.h>
#include <hip/hip_bf16.h>
#include <math.h>

// Problem constants
#define ROWS 256000     // B*S = 512*500
#define BATCH 512

// prep region (float offsets in ws, always f32)
#define OFF_TK   0          // tk [50][50]
#define OFF_WVT  2512       // WvT [4000][200]
#define OFF_WT   802512     // WT  [200][400]  (We.T | Wa.T)
#define OFF_W1T  882512     // W1T [250][128]  (zero-padded u>=100)
#define OFF_W2T  914512     // W2T [100][52]   (zero-padded f>=50)
#define PREP_FLOATS 919712

// output layout (float offsets)
#define OUT_MAST 12800000
#define OUT_LOG  13056000
#define OUT_PROB 14080000

// storage-type helpers (big intermediate arrays may be f32 or bf16)
__device__ inline float ldT(const float* p) { return *p; }
__device__ inline float ldT(const __hip_bfloat16* p) { return __bfloat162float(*p); }
__device__ inline void stT(float* p, float v) { *p = v; }
__device__ inline void stT(__hip_bfloat16* p, float v) { *p = __float2bfloat16(v); }

// ---------------------------------------------------------------- prep ----
__global__ __launch_bounds__(256) void prep_kernel(
    const float* __restrict__ keymem, const float* __restrict__ Wk,
    const float* __restrict__ bk, const float* __restrict__ Wv,
    const float* __restrict__ We, const float* __restrict__ Wa,
    const float* __restrict__ W1, const float* __restrict__ W2,
    float* __restrict__ ws) {
  int idx = blockIdx.x * 256 + threadIdx.x;
  if (idx < 2500) {                      // tk[m][k] = sum_l km[l][k]*Wk[m][l] + bk[m]
    int m = idx / 50, k = idx - m * 50;
    float acc = bk[m];
    for (int l = 0; l < 50; ++l) acc = fmaf(keymem[l*50 + k], Wk[m*50 + l], acc);
    ws[OFF_TK + m*50 + k] = acc;
    return;
  }
  idx -= 2500;
  if (idx < 800000) {                    // WvT[j][v] = Wv[v][j]
    int j = idx / 200, v = idx - j * 200;
    ws[OFF_WVT + j*200 + v] = Wv[v*4000 + j];
    return;
  }
  idx -= 800000;
  if (idx < 80000) {                     // WT[v][c]
    int v = idx / 400, c = idx - v * 400;
    ws[OFF_WT + v*400 + c] = (c < 200) ? We[c*200 + v] : Wa[(c-200)*200 + v];
    return;
  }
  idx -= 80000;
  if (idx < 32000) {                     // W1T[j][u], [250][128]
    int j = idx / 128, u = idx - j * 128;
    ws[OFF_W1T + j*128 + u] = (u < 100) ? W1[u*250 + j] : 0.f;
    return;
  }
  idx -= 32000;
  if (idx < 5200) {                      // W2T[j][f], [100][52]
    int j = idx / 52, f = idx - j * 52;
    ws[OFF_W2T + j*52 + f] = (f < 50) ? W2[f*100 + j] : 0.f;
    return;
  }
}

// ---------------------------------------------------------------- attn ----
// wave per (b,t) row; 4 waves per block; attn buffer is chunk-local
template <typename T>
__global__ __launch_bounds__(256) void attn_kernel(
    const int* __restrict__ questions, const float* __restrict__ qtab,
    const float* __restrict__ Wq, const float* __restrict__ bq,
    const float* __restrict__ ws, T* __restrict__ attn, int row0) {
  __shared__ float qe_s[4][52];
  __shared__ float qu_s[4][52];
  int w = threadIdx.x >> 6;
  int lane = threadIdx.x & 63;
  int lrow = blockIdx.x * 4 + w;
  int row = row0 + lrow;
  int qi = questions[row];
  if (lane < 50) qe_s[w][lane] = qtab[qi*50 + lane];
  __syncthreads();
  if (lane < 50) {
    float acc = bq[lane];
    const float* wq = Wq + lane*50;
    #pragma unroll
    for (int j = 0; j < 50; ++j) acc = fmaf(qe_s[w][j], wq[j], acc);
    qu_s[w][lane] = tanhf(acc);
  }
  __syncthreads();
  float sc = -3.0e38f;
  if (lane < 50) {
    float acc = 0.f;
    const float* tkr = ws + OFF_TK + lane*50;
    #pragma unroll
    for (int k = 0; k < 50; ++k) acc = fmaf(qu_s[w][k], tkr[k], acc);
    sc = acc;
  }
  float mx = sc;
  #pragma unroll
  for (int d = 32; d > 0; d >>= 1) mx = fmaxf(mx, __shfl_xor(mx, d));
  float ex = (lane < 50) ? __expf(sc - mx) : 0.f;
  float sm = ex;
  #pragma unroll
  for (int d = 32; d > 0; d >>= 1) sm += __shfl_xor(sm, d);
  if (lane < 50) stT(&attn[lrow*50 + lane], ex / sm);
}

// ------------------------------------------------------------ erase/add ----
// 32 rows per block; C[32 x 400] = VE[32 x 200] @ WT[200 x 400]; er/ad chunk-local
template <typename T>
__global__ __launch_bounds__(256) void ea_kernel(
    const int* __restrict__ questions, const int* __restrict__ responses,
    const float* __restrict__ bv, const float* __restrict__ be,
    const float* __restrict__ ba, const float* __restrict__ ws,
    T* __restrict__ er, T* __restrict__ ad, int row0) {
  __shared__ float ve_s[32][200];
  int tid = threadIdx.x;
  int lrow0 = blockIdx.x * 32;
  const float* wvt = ws + OFF_WVT;
  for (int i = tid; i < 6400; i += 256) {
    int r = i / 200, v = i - r * 200;
    int row = row0 + lrow0 + r;
    int qi = questions[row];
    float acc = bv[v];
    if (qi > 0) {
      int resp = responses[row];
      const float* base = wvt + (qi - 1) * 200 + v;
      #pragma unroll
      for (int c = 0; c < 4; ++c) {
        float wgt = 1.f - fabsf((float)(c - resp)) * (1.f / 3.f);
        if (wgt > 0.f) acc = fmaf(wgt, base[c * 200000], acc);
      }
    }
    ve_s[r][v] = acc;
  }
  __syncthreads();
  const float* wt = ws + OFF_WT;
  float acc0[32], acc1[32];
  #pragma unroll
  for (int r = 0; r < 32; ++r) { acc0[r] = 0.f; acc1[r] = 0.f; }
  int c0 = tid, c1 = tid + 256;
  bool has1 = (c1 < 400);
  for (int v = 0; v < 200; ++v) {
    float w0 = wt[v*400 + c0];
    float w1 = has1 ? wt[v*400 + c1] : 0.f;
    #pragma unroll
    for (int r = 0; r < 32; ++r) {
      float h = ve_s[r][v];
      acc0[r] = fmaf(h, w0, acc0[r]);
      acc1[r] = fmaf(h, w1, acc1[r]);
    }
  }
  if (c0 < 200) {
    float bias = be[c0];
    #pragma unroll
    for (int r = 0; r < 32; ++r) {
      float x = acc0[r] + bias;
      stT(&er[(lrow0 + r)*200 + c0], 1.f / (1.f + __expf(-x)));
    }
  } else {
    float bias = ba[c0 - 200];
    #pragma unroll
    for (int r = 0; r < 32; ++r)
      stT(&ad[(lrow0 + r)*200 + (c0 - 200)], tanhf(acc0[r] + bias));
  }
  if (has1) {
    float bias = ba[c1 - 200];
    #pragma unroll
    for (int r = 0; r < 32; ++r)
      stT(&ad[(lrow0 + r)*200 + (c1 - 200)], tanhf(acc1[r] + bias));
  }
}

// ------------------------------------------------------------ recurrence ----
// grid = (batch_per_chunk, 4 v-groups); ONE wave per block, no LDS, no barriers.
// Lane l (<50) owns column v = vg*50+l across all 50 memory slots (in regs).
// attn[t] is broadcast from lane m via v_readlane (wave-uniform SGPR operand).
// Depth-3 register prefetch of er/ad/attn covers L2/L3 latency.
__device__ inline float lane_bcast(float x, int m) {
  return __uint_as_float(__builtin_amdgcn_readlane(__float_as_uint(x), m));
}

template <typename T>
__global__ __launch_bounds__(64) void rec_kernel(
    const float* __restrict__ ivm, const T* __restrict__ attn,
    const T* __restrict__ er, const T* __restrict__ ad,
    T* __restrict__ rd) {
  const int lane = threadIdx.x;            // 0..63
  const int b    = blockIdx.x;             // chunk-local batch element
  const int vg   = blockIdx.y;             // 0..3
  const int v    = vg * 50 + lane;         // valid if lane<50
  const bool av  = lane < 50;
  const long base = (long)b * 500;

  float vm[50];
  #pragma unroll
  for (int m = 0; m < 50; ++m) vm[m] = 0.f;
  if (av) {
    #pragma unroll
    for (int m = 0; m < 50; ++m) vm[m] = ivm[m*200 + v];
  }

  const T* erp = er   + base*200 + v;      // column-v stream, stride 200
  const T* adp = ad   + base*200 + v;
  const T* atp = attn + base*50  + lane;   // lane m streams attn[.,m]
  T*       rdp = rd   + base*200 + v;

  // software pipeline: slots 0(current),1,2 + incoming 3
  float e0=0,a0=0,t0=0, e1=0,a1=0,t1=0, e2=0,a2=0,t2=0;
  if (av) {
    e0 = ldT(erp);       a0 = ldT(adp);       t0 = ldT(atp);
    e1 = ldT(erp + 200); a1 = ldT(adp + 200); t1 = ldT(atp + 50);
    e2 = ldT(erp + 400); a2 = ldT(adp + 400); t2 = ldT(atp + 100);
  }
  const T* erf = erp + 600;
  const T* adf = adp + 600;
  const T* atf = atp + 150;

  for (int t = 0; t < 500; ++t) {
    // prefetch t+3
    float e3 = 0.f, a3 = 0.f, t3 = 0.f;
    if (av && t < 497) { e3 = ldT(erf); a3 = ldT(adf); t3 = ldT(atf); }
    erf += 200; adf += 200; atf += 50;

    // compute step t: read (pre-update) + memory update, 4-way split reduction
    float r0 = 0.f, r1 = 0.f, r2 = 0.f, r3 = 0.f;
    #pragma unroll
    for (int m = 0; m < 50; m += 4) {
      {
        float am = lane_bcast(t0, m);
        r0 = fmaf(am, vm[m], r0);
        float w = fmaf(-vm[m], e0, a0);
        vm[m] = fmaf(am, w, vm[m]);
      }
      {
        float am = lane_bcast(t0, m + 1);
        r1 = fmaf(am, vm[m+1], r1);
        float w = fmaf(-vm[m+1], e0, a0);
        vm[m+1] = fmaf(am, w, vm[m+1]);
      }
      if (m + 2 < 50) {
        float am = lane_bcast(t0, m + 2);
        r2 = fmaf(am, vm[m+2], r2);
        float w = fmaf(-vm[m+2], e0, a0);
        vm[m+2] = fmaf(am, w, vm[m+2]);
      }
      if (m + 3 < 50) {
        float am = lane_bcast(t0, m + 3);
        r3 = fmaf(am, vm[m+3], r3);
        float w = fmaf(-vm[m+3], e0, a0);
        vm[m+3] = fmaf(am, w, vm[m+3]);
      }
    }
    if (av) stT(rdp, (r0 + r1) + (r2 + r3));
    rdp += 200;

    // rotate pipeline
    e0 = e1; a0 = a1; t0 = t1;
    e1 = e2; a1 = a2; t1 = t2;
    e2 = e3; a2 = a3; t2 = t3;
  }
}

// ---------------------------------------------------------------- MLP ----
// 64 rows/block, 512 threads; GEMM1 [64x128] K=250 (4x4 reg tile), GEMM2 [64x52] K=100
#define W1S 0
#define HS  6400
#define Z1S 0
#define W2S 6656
#define FTS 11856

template <typename T>
__global__ __launch_bounds__(512) void mlp_kernel(
    const int* __restrict__ questions, const float* __restrict__ qtab,
    const float* __restrict__ b1, const float* __restrict__ b2,
    const float* __restrict__ Wo, const float* __restrict__ bo,
    const float* __restrict__ ws, const T* __restrict__ rd,
    float* __restrict__ out, int row0) {
  __shared__ __align__(16) float smem[15184];
  int tid = threadIdx.x;
  int lrow0 = blockIdx.x * 64;
  const float* w1t = ws + OFF_W1T;
  int ug = tid & 31, rg = tid >> 5;
  int u0 = ug * 4, r0 = rg * 4;
  float acc[4][4];
  #pragma unroll
  for (int i = 0; i < 4; ++i)
    #pragma unroll
    for (int j = 0; j < 4; ++j) acc[i][j] = 0.f;

  for (int kt = 0; kt < 5; ++kt) {
    int j0 = kt * 50;
    for (int i = tid; i < 6400; i += 512)        // W1T tile [50][128]
      smem[W1S + i] = w1t[j0*128 + i];
    for (int i = tid; i < 3200; i += 512) {      // h tile [64][50]
      int r = i / 50, jj = i - r * 50;
      int lrow = lrow0 + r;
      int j = j0 + jj;
      float hv;
      if (j < 200) hv = ldT(&rd[lrow*200 + j]);
      else         hv = qtab[questions[row0 + lrow]*50 + (j - 200)];
      smem[HS + r*50 + jj] = hv;
    }
    __syncthreads();
    #pragma unroll 2
    for (int jj = 0; jj < 50; ++jj) {
      float4 wv = *(const float4*)&smem[W1S + jj*128 + u0];
      #pragma unroll
      for (int rr = 0; rr < 4; ++rr) {
        float h = smem[HS + (r0 + rr)*50 + jj];
        acc[rr][0] = fmaf(h, wv.x, acc[rr][0]);
        acc[rr][1] = fmaf(h, wv.y, acc[rr][1]);
        acc[rr][2] = fmaf(h, wv.z, acc[rr][2]);
        acc[rr][3] = fmaf(h, wv.w, acc[rr][3]);
      }
    }
    __syncthreads();
  }
  // z1 = relu(acc + b1) into LDS [64][104]
  if (u0 < 100) {
    #pragma unroll
    for (int uu = 0; uu < 4; ++uu) {
      int u = u0 + uu;
      float bb = b1[u];
      #pragma unroll
      for (int rr = 0; rr < 4; ++rr) {
        float z = acc[rr][uu] + bb;
        smem[Z1S + (r0 + rr)*104 + u] = fmaxf(z, 0.f);
      }
    }
  }
  for (int i = tid; i < 5200; i += 512)          // W2T [100][52]
    smem[W2S + i] = ws[OFF_W2T + i];
  __syncthreads();
  // GEMM2: feat [64][50]
  for (int i = tid; i < 832; i += 512) {
    int r = i / 13, fg = i - r * 13;
    int f0 = fg * 4;
    float a0 = 0.f, a1 = 0.f, a2 = 0.f, a3 = 0.f;
    #pragma unroll 4
    for (int j = 0; j < 100; ++j) {
      float z = smem[Z1S + r*104 + j];
      float4 wv = *(const float4*)&smem[W2S + j*52 + f0];
      a0 = fmaf(z, wv.x, a0);
      a1 = fmaf(z, wv.y, a1);
      a2 = fmaf(z, wv.z, a2);
      a3 = fmaf(z, wv.w, a3);
    }
    int row = row0 + lrow0 + r;
    float vals[4] = {a0, a1, a2, a3};
    #pragma unroll
    for (int ff = 0; ff < 4; ++ff) {
      int f = f0 + ff;
      if (f < 50) {
        float val = vals[ff] + b2[f];
        smem[FTS + r*52 + f] = val;
        out[row*50 + f] = val;
      }
    }
  }
  __syncthreads();
  // mastery / logits / probs
  if (tid < 64) {
    int r = tid, row = row0 + lrow0 + r;
    float s = 0.f;
    float lg[4] = {bo[0], bo[1], bo[2], bo[3]};
    #pragma unroll
    for (int f = 0; f < 50; ++f) {
      float ft = smem[FTS + r*52 + f];
      s += ft;
      #pragma unroll
      for (int c = 0; c < 4; ++c) lg[c] = fmaf(Wo[c*50 + f], ft, lg[c]);
    }
    out[OUT_MAST + row] = s * (1.f / 50.f);
    float mx = fmaxf(fmaxf(lg[0], lg[1]), fmaxf(lg[2], lg[3]));
    float e0 = __expf(lg[0] - mx), e1 = __expf(lg[1] - mx);
    float e2 = __expf(lg[2] - mx), e3 = __expf(lg[3] - mx);
    float inv = 1.f / (e0 + e1 + e2 + e3);
    #pragma unroll
    for (int c = 0; c < 4; ++c) out[OUT_LOG + row*4 + c] = lg[c];
    out[OUT_PROB + row*4 + 0] = e0 * inv;
    out[OUT_PROB + row*4 + 1] = e1 * inv;
    out[OUT_PROB + row*4 + 2] = e2 * inv;
    out[OUT_PROB + row*4 + 3] = e3 * inv;
  }
}

// ---------------------------------------------------------------- launch ----
// nc = number of batch chunks; scratch holds one chunk's attn/er/ad/rd.
template <typename T>
static void launch_pipeline(const int* questions, const int* responses,
                            const float* qtab, const float* Wv, const float* bv,
                            const float* keymem, const float* ivm,
                            const float* Wq, const float* bq,
                            const float* Wk, const float* bk,
                            const float* We, const float* be,
                            const float* Wa, const float* ba,
                            const float* W1, const float* b1,
                            const float* W2, const float* b2,
                            const float* Wo, const float* bo,
                            float* ws, float* out, int nc, hipStream_t stream) {
  const int RPC = ROWS / nc;          // rows per chunk
  const int BPC = BATCH / nc;         // batch elems per chunk
  T* attn = (T*)((char*)ws + (size_t)PREP_FLOATS * 4);
  T* er   = attn + (size_t)RPC * 50;
  T* ad   = er   + (size_t)RPC * 200;
  T* rd   = ad   + (size_t)RPC * 200;

  prep_kernel<<<3593, 256, 0, stream>>>(keymem, Wk, bk, Wv, We, Wa, W1, W2, ws);
  for (int c = 0; c < nc; ++c) {
    int row0 = c * RPC;
    attn_kernel<T><<<RPC/4,  256, 0, stream>>>(questions, qtab, Wq, bq, ws, attn, row0);
    ea_kernel<T>  <<<RPC/32, 256, 0, stream>>>(questions, responses, bv, be, ba, ws, er, ad, row0);
    rec_kernel<T> <<<dim3(BPC, 4), 64, 0, stream>>>(ivm, attn, er, ad, rd);
    mlp_kernel<T> <<<RPC/64, 512, 0, stream>>>(questions, qtab, b1, b2, Wo, bo, ws, rd, out, row0);
  }
}

extern "C" void kernel_launch(void* const* d_in, const int* in_sizes, int n_in,
                              void* d_out, int out_size, void* d_ws, size_t ws_size,
                              hipStream_t stream) {
  const int*   questions = (const int*)d_in[0];
  const int*   responses = (const int*)d_in[1];
  const float* qtab      = (const float*)d_in[2];
  const float* Wv        = (const float*)d_in[3];
  const float* bv        = (const float*)d_in[4];
  const float* keymem    = (const float*)d_in[5];
  const float* ivm       = (const float*)d_in[6];
  const float* Wq        = (const float*)d_in[7];
  const float* bq        = (const float*)d_in[8];
  const float* Wk        = (const float*)d_in[9];
  const float* bk        = (const float*)d_in[10];
  const float* We        = (const float*)d_in[11];
  const float* be        = (const float*)d_in[12];
  const float* Wa        = (const float*)d_in[13];
  const float* ba        = (const float*)d_in[14];
  const float* W1        = (const float*)d_in[15];
  const float* b1        = (const float*)d_in[16];
  const float* W2        = (const float*)d_in[17];
  const float* b2        = (const float*)d_in[18];
  const float* Wo        = (const float*)d_in[19];
  const float* bo        = (const float*)d_in[20];
  float* ws  = (float*)d_ws;
  float* out = (float*)d_out;

  // scratch need: prep + (ROWS/nc) * (50 + 3*200) elements of storage type T
  const size_t prep_b = (size_t)PREP_FLOATS * 4;
  auto need = [&](size_t esz, int nc) {
    return prep_b + ((size_t)ROWS / nc) * 650 * esz;
  };

  if (ws_size >= need(4, 1)) {          // 669 MB: full f32
    launch_pipeline<float>(questions, responses, qtab, Wv, bv, keymem, ivm,
                           Wq, bq, Wk, bk, We, be, Wa, ba, W1, b1, W2, b2,
                           Wo, bo, ws, out, 1, stream);
  } else if (ws_size >= need(2, 1)) {   // 336 MB: full bf16
    launch_pipeline<__hip_bfloat16>(questions, responses, qtab, Wv, bv, keymem, ivm,
                                    Wq, bq, Wk, bk, We, be, Wa, ba, W1, b1, W2, b2,
                                    Wo, bo, ws, out, 1, stream);
  } else if (ws_size >= need(2, 4)) {   // 87 MB: bf16, 4 chunks
    launch_pipeline<__hip_bfloat16>(questions, responses, qtab, Wv, bv, keymem, ivm,
                                    Wq, bq, Wk, bk, We, be, Wa, ba, W1, b1, W2, b2,
                                    Wo, bo, ws, out, 4, stream);
  } else {                              // 24.5 MB: bf16, 16 chunks (last resort)
    launch_pipeline<__hip_bfloat16>(questions, responses, qtab, Wv, bv, keymem, ivm,
                                    Wq, bq, Wk, bk, We, be, Wa, ba, W1, b1, W2, b2,
                                    Wo, bo, ws, out, 16, stream);
  }
}

// Round 8
// 2420.029 us; speedup vs baseline: 1.4936x; 1.3830x over previous
//
#include <hip/hip_runtime.h>
#include <hip/hip_bf16.h>
#include <math.h>

// Problem constants
#define ROWS 256000     // B*S = 512*500
#define BATCH 512

// prep region (float offsets in ws, always f32)
#define OFF_TK   0          // tk [50][50]
#define OFF_WVT  2512       // WvT [4000][200]
#define OFF_WT   802512     // WT  [200][400]  (We.T | Wa.T)
#define OFF_W1T  882512     // W1T [250][128]  (zero-padded u>=100)
#define OFF_W2T  914512     // W2T [100][52]   (zero-padded f>=50)
#define PREP_FLOATS 919712

// output layout (float offsets)
#define OUT_MAST 12800000
#define OUT_LOG  13056000
#define OUT_PROB 14080000

typedef __hip_bfloat16 bf16;
__device__ inline float ldT(const bf16* p) { return __bfloat162float(*p); }
__device__ inline void stT(bf16* p, float v) { *p = __float2bfloat16(v); }

// ---------------------------------------------------------------- prep ----
__global__ __launch_bounds__(256) void prep_kernel(
    const float* __restrict__ keymem, const float* __restrict__ Wk,
    const float* __restrict__ bk, const float* __restrict__ Wv,
    const float* __restrict__ We, const float* __restrict__ Wa,
    const float* __restrict__ W1, const float* __restrict__ W2,
    float* __restrict__ ws) {
  int idx = blockIdx.x * 256 + threadIdx.x;
  if (idx < 2500) {                      // tk[m][k] = sum_l km[l][k]*Wk[m][l] + bk[m]
    int m = idx / 50, k = idx - m * 50;
    float acc = bk[m];
    for (int l = 0; l < 50; ++l) acc = fmaf(keymem[l*50 + k], Wk[m*50 + l], acc);
    ws[OFF_TK + m*50 + k] = acc;
    return;
  }
  idx -= 2500;
  if (idx < 800000) {                    // WvT[j][v] = Wv[v][j]
    int j = idx / 200, v = idx - j * 200;
    ws[OFF_WVT + j*200 + v] = Wv[v*4000 + j];
    return;
  }
  idx -= 800000;
  if (idx < 80000) {                     // WT[v][c]
    int v = idx / 400, c = idx - v * 400;
    ws[OFF_WT + v*400 + c] = (c < 200) ? We[c*200 + v] : Wa[(c-200)*200 + v];
    return;
  }
  idx -= 80000;
  if (idx < 32000) {                     // W1T[j][u], [250][128]
    int j = idx / 128, u = idx - j * 128;
    ws[OFF_W1T + j*128 + u] = (u < 100) ? W1[u*250 + j] : 0.f;
    return;
  }
  idx -= 32000;
  if (idx < 5200) {                      // W2T[j][f], [100][52]
    int j = idx / 52, f = idx - j * 52;
    ws[OFF_W2T + j*52 + f] = (f < 50) ? W2[f*100 + j] : 0.f;
    return;
  }
}

// ---------------------------------------------------------------- attn ----
// wave per (b,t) row; 4 waves per block; attn buffer is chunk-local
__global__ __launch_bounds__(256) void attn_kernel(
    const int* __restrict__ questions, const float* __restrict__ qtab,
    const float* __restrict__ Wq, const float* __restrict__ bq,
    const float* __restrict__ ws, bf16* __restrict__ attn, int row0) {
  __shared__ float qe_s[4][52];
  __shared__ float qu_s[4][52];
  int w = threadIdx.x >> 6;
  int lane = threadIdx.x & 63;
  int lrow = blockIdx.x * 4 + w;
  int row = row0 + lrow;
  int qi = questions[row];
  if (lane < 50) qe_s[w][lane] = qtab[qi*50 + lane];
  __syncthreads();
  if (lane < 50) {
    float acc = bq[lane];
    const float* wq = Wq + lane*50;
    #pragma unroll
    for (int j = 0; j < 50; ++j) acc = fmaf(qe_s[w][j], wq[j], acc);
    qu_s[w][lane] = tanhf(acc);
  }
  __syncthreads();
  float sc = -3.0e38f;
  if (lane < 50) {
    float acc = 0.f;
    const float* tkr = ws + OFF_TK + lane*50;
    #pragma unroll
    for (int k = 0; k < 50; ++k) acc = fmaf(qu_s[w][k], tkr[k], acc);
    sc = acc;
  }
  float mx = sc;
  #pragma unroll
  for (int d = 32; d > 0; d >>= 1) mx = fmaxf(mx, __shfl_xor(mx, d));
  float ex = (lane < 50) ? __expf(sc - mx) : 0.f;
  float sm = ex;
  #pragma unroll
  for (int d = 32; d > 0; d >>= 1) sm += __shfl_xor(sm, d);
  if (lane < 50) stT(&attn[lrow*50 + lane], ex / sm);
}

// ------------------------------------------------------------ erase/add ----
// 32 rows per block; C[32 x 400] = VE[32 x 200] @ WT[200 x 400]; er/ad chunk-local
__global__ __launch_bounds__(256) void ea_kernel(
    const int* __restrict__ questions, const int* __restrict__ responses,
    const float* __restrict__ bv, const float* __restrict__ be,
    const float* __restrict__ ba, const float* __restrict__ ws,
    bf16* __restrict__ er, bf16* __restrict__ ad, int row0) {
  __shared__ float ve_s[32][200];
  int tid = threadIdx.x;
  int lrow0 = blockIdx.x * 32;
  const float* wvt = ws + OFF_WVT;
  for (int i = tid; i < 6400; i += 256) {
    int r = i / 200, v = i - r * 200;
    int row = row0 + lrow0 + r;
    int qi = questions[row];
    float acc = bv[v];
    if (qi > 0) {
      int resp = responses[row];
      const float* base = wvt + (qi - 1) * 200 + v;
      #pragma unroll
      for (int c = 0; c < 4; ++c) {
        float wgt = 1.f - fabsf((float)(c - resp)) * (1.f / 3.f);
        if (wgt > 0.f) acc = fmaf(wgt, base[c * 200000], acc);
      }
    }
    ve_s[r][v] = acc;
  }
  __syncthreads();
  const float* wt = ws + OFF_WT;
  float acc0[32], acc1[32];
  #pragma unroll
  for (int r = 0; r < 32; ++r) { acc0[r] = 0.f; acc1[r] = 0.f; }
  int c0 = tid, c1 = tid + 256;
  bool has1 = (c1 < 400);
  for (int v = 0; v < 200; ++v) {
    float w0 = wt[v*400 + c0];
    float w1 = has1 ? wt[v*400 + c1] : 0.f;
    #pragma unroll
    for (int r = 0; r < 32; ++r) {
      float h = ve_s[r][v];
      acc0[r] = fmaf(h, w0, acc0[r]);
      acc1[r] = fmaf(h, w1, acc1[r]);
    }
  }
  if (c0 < 200) {
    float bias = be[c0];
    #pragma unroll
    for (int r = 0; r < 32; ++r) {
      float x = acc0[r] + bias;
      stT(&er[(lrow0 + r)*200 + c0], 1.f / (1.f + __expf(-x)));
    }
  } else {
    float bias = ba[c0 - 200];
    #pragma unroll
    for (int r = 0; r < 32; ++r)
      stT(&ad[(lrow0 + r)*200 + (c0 - 200)], tanhf(acc0[r] + bias));
  }
  if (has1) {
    float bias = ba[c1 - 200];
    #pragma unroll
    for (int r = 0; r < 32; ++r)
      stT(&ad[(lrow0 + r)*200 + (c1 - 200)], tanhf(acc1[r] + bias));
  }
}

// ------------------------------------------------------------ recurrence ----
// grid = (batch_per_chunk, 4 v-groups); ONE wave per block, no LDS, no barriers.
// Lane l (<50) owns column v = vg*50+l; vm[50] in registers.
// attn broadcast via v_readlane. Unroll-4 circular buffer => loads issued 3
// iterations before use (compile-time slots, no register rotation, counted vmcnt).
// rd is written IN PLACE over ad: rd[t] overwrites ad[t], which was loaded at
// iteration t-3 and never re-read (ad[t+3] is loaded BEFORE the rd[t] store).
__device__ inline float lane_bcast(float x, int m) {
  return __uint_as_float(__builtin_amdgcn_readlane(__float_as_uint(x), m));
}

__global__ __launch_bounds__(64) void rec_kernel(
    const float* __restrict__ ivm, const bf16* __restrict__ attn,
    const bf16* __restrict__ er, bf16* __restrict__ ad_rd) {
  const int lane = threadIdx.x;            // 0..63
  const int b    = blockIdx.x;             // chunk-local batch element
  const int vg   = blockIdx.y;             // 0..3
  const int v    = vg * 50 + lane;         // valid if lane<50
  const bool av  = lane < 50;
  const long base = (long)b * 500;

  float vm[50];
  #pragma unroll
  for (int m = 0; m < 50; ++m) vm[m] = 0.f;
  if (av) {
    #pragma unroll
    for (int m = 0; m < 50; ++m) vm[m] = ivm[m*200 + v];
  }

  const bf16* erp = er    + base*200 + v;  // column-v stream, stride 200
  bf16*       adp = ad_rd + base*200 + v;  // ad in, rd out (same slots)
  const bf16* atp = attn  + base*50  + lane;

  float eb[4], ab[4], tb[4];
  #pragma unroll
  for (int j = 0; j < 4; ++j) { eb[j] = 0.f; ab[j] = 0.f; tb[j] = 0.f; }
  if (av) {
    #pragma unroll
    for (int j = 0; j < 3; ++j) {          // preload steps 0,1,2
      eb[j] = ldT(erp + j*200);
      ab[j] = ldT(adp + j*200);
      tb[j] = ldT(atp + j*50);
    }
  }

  // main: t = 0..495 (loads for steps 3..498, always in range)
  for (int t4 = 0; t4 < 124; ++t4) {
    #pragma unroll
    for (int j = 0; j < 4; ++j) {
      const int t  = t4*4 + j;
      const int cs = j;                    // consume slot (t % 4)
      const int ls = (j + 3) & 3;          // load slot ((t+3) % 4)
      if (av) {
        eb[ls] = ldT(erp + (t+3)*200);
        ab[ls] = ldT(adp + (t+3)*200);
        tb[ls] = ldT(atp + (t+3)*50);
      }
      float e0 = eb[cs], a0 = ab[cs], t0 = tb[cs];
      float r0 = 0.f, r1 = 0.f, r2 = 0.f, r3 = 0.f;
      #pragma unroll
      for (int m = 0; m < 48; m += 4) {
        float am0 = lane_bcast(t0, m);
        r0 = fmaf(am0, vm[m], r0);
        vm[m] = fmaf(am0, fmaf(-vm[m], e0, a0), vm[m]);
        float am1 = lane_bcast(t0, m + 1);
        r1 = fmaf(am1, vm[m+1], r1);
        vm[m+1] = fmaf(am1, fmaf(-vm[m+1], e0, a0), vm[m+1]);
        float am2 = lane_bcast(t0, m + 2);
        r2 = fmaf(am2, vm[m+2], r2);
        vm[m+2] = fmaf(am2, fmaf(-vm[m+2], e0, a0), vm[m+2]);
        float am3 = lane_bcast(t0, m + 3);
        r3 = fmaf(am3, vm[m+3], r3);
        vm[m+3] = fmaf(am3, fmaf(-vm[m+3], e0, a0), vm[m+3]);
      }
      {
        float am0 = lane_bcast(t0, 48);
        r0 = fmaf(am0, vm[48], r0);
        vm[48] = fmaf(am0, fmaf(-vm[48], e0, a0), vm[48]);
        float am1 = lane_bcast(t0, 49);
        r1 = fmaf(am1, vm[49], r1);
        vm[49] = fmaf(am1, fmaf(-vm[49], e0, a0), vm[49]);
      }
      if (av) stT(adp + t*200, (r0 + r1) + (r2 + r3));   // rd[t] over ad[t]
    }
  }
  // epilogue: t = 496..499 (only t=496 still loads, step 499)
  #pragma unroll
  for (int j = 0; j < 4; ++j) {
    const int t  = 496 + j;
    const int cs = j;
    const int ls = (j + 3) & 3;
    if (j == 0 && av) {
      eb[ls] = ldT(erp + 499*200);
      ab[ls] = ldT(adp + 499*200);
      tb[ls] = ldT(atp + 499*50);
    }
    float e0 = eb[cs], a0 = ab[cs], t0 = tb[cs];
    float r0 = 0.f, r1 = 0.f, r2 = 0.f, r3 = 0.f;
    #pragma unroll
    for (int m = 0; m < 48; m += 4) {
      float am0 = lane_bcast(t0, m);
      r0 = fmaf(am0, vm[m], r0);
      vm[m] = fmaf(am0, fmaf(-vm[m], e0, a0), vm[m]);
      float am1 = lane_bcast(t0, m + 1);
      r1 = fmaf(am1, vm[m+1], r1);
      vm[m+1] = fmaf(am1, fmaf(-vm[m+1], e0, a0), vm[m+1]);
      float am2 = lane_bcast(t0, m + 2);
      r2 = fmaf(am2, vm[m+2], r2);
      vm[m+2] = fmaf(am2, fmaf(-vm[m+2], e0, a0), vm[m+2]);
      float am3 = lane_bcast(t0, m + 3);
      r3 = fmaf(am3, vm[m+3], r3);
      vm[m+3] = fmaf(am3, fmaf(-vm[m+3], e0, a0), vm[m+3]);
    }
    {
      float am0 = lane_bcast(t0, 48);
      r0 = fmaf(am0, vm[48], r0);
      vm[48] = fmaf(am0, fmaf(-vm[48], e0, a0), vm[48]);
      float am1 = lane_bcast(t0, 49);
      r1 = fmaf(am1, vm[49], r1);
      vm[49] = fmaf(am1, fmaf(-vm[49], e0, a0), vm[49]);
    }
    if (av) stT(adp + t*200, (r0 + r1) + (r2 + r3));
  }
}

// ---------------------------------------------------------------- MLP ----
// 64 rows/block, 512 threads; GEMM1 [64x128] K=250 (4x4 reg tile), GEMM2 [64x52] K=100
#define W1S 0
#define HS  6400
#define Z1S 0
#define W2S 6656
#define FTS 11856

__global__ __launch_bounds__(512) void mlp_kernel(
    const int* __restrict__ questions, const float* __restrict__ qtab,
    const float* __restrict__ b1, const float* __restrict__ b2,
    const float* __restrict__ Wo, const float* __restrict__ bo,
    const float* __restrict__ ws, const bf16* __restrict__ rd,
    float* __restrict__ out, int row0) {
  __shared__ __align__(16) float smem[15184];
  int tid = threadIdx.x;
  int lrow0 = blockIdx.x * 64;
  const float* w1t = ws + OFF_W1T;
  int ug = tid & 31, rg = tid >> 5;
  int u0 = ug * 4, r0 = rg * 4;
  float acc[4][4];
  #pragma unroll
  for (int i = 0; i < 4; ++i)
    #pragma unroll
    for (int j = 0; j < 4; ++j) acc[i][j] = 0.f;

  for (int kt = 0; kt < 5; ++kt) {
    int j0 = kt * 50;
    for (int i = tid; i < 6400; i += 512)        // W1T tile [50][128]
      smem[W1S + i] = w1t[j0*128 + i];
    for (int i = tid; i < 3200; i += 512) {      // h tile [64][50]
      int r = i / 50, jj = i - r * 50;
      int lrow = lrow0 + r;
      int j = j0 + jj;
      float hv;
      if (j < 200) hv = ldT(&rd[lrow*200 + j]);
      else         hv = qtab[questions[row0 + lrow]*50 + (j - 200)];
      smem[HS + r*50 + jj] = hv;
    }
    __syncthreads();
    #pragma unroll 2
    for (int jj = 0; jj < 50; ++jj) {
      float4 wv = *(const float4*)&smem[W1S + jj*128 + u0];
      #pragma unroll
      for (int rr = 0; rr < 4; ++rr) {
        float h = smem[HS + (r0 + rr)*50 + jj];
        acc[rr][0] = fmaf(h, wv.x, acc[rr][0]);
        acc[rr][1] = fmaf(h, wv.y, acc[rr][1]);
        acc[rr][2] = fmaf(h, wv.z, acc[rr][2]);
        acc[rr][3] = fmaf(h, wv.w, acc[rr][3]);
      }
    }
    __syncthreads();
  }
  // z1 = relu(acc + b1) into LDS [64][104]
  if (u0 < 100) {
    #pragma unroll
    for (int uu = 0; uu < 4; ++uu) {
      int u = u0 + uu;
      float bb = b1[u];
      #pragma unroll
      for (int rr = 0; rr < 4; ++rr) {
        float z = acc[rr][uu] + bb;
        smem[Z1S + (r0 + rr)*104 + u] = fmaxf(z, 0.f);
      }
    }
  }
  for (int i = tid; i < 5200; i += 512)          // W2T [100][52]
    smem[W2S + i] = ws[OFF_W2T + i];
  __syncthreads();
  // GEMM2: feat [64][50]
  for (int i = tid; i < 832; i += 512) {
    int r = i / 13, fg = i - r * 13;
    int f0 = fg * 4;
    float a0 = 0.f, a1 = 0.f, a2 = 0.f, a3 = 0.f;
    #pragma unroll 4
    for (int j = 0; j < 100; ++j) {
      float z = smem[Z1S + r*104 + j];
      float4 wv = *(const float4*)&smem[W2S + j*52 + f0];
      a0 = fmaf(z, wv.x, a0);
      a1 = fmaf(z, wv.y, a1);
      a2 = fmaf(z, wv.z, a2);
      a3 = fmaf(z, wv.w, a3);
    }
    int row = row0 + lrow0 + r;
    float vals[4] = {a0, a1, a2, a3};
    #pragma unroll
    for (int ff = 0; ff < 4; ++ff) {
      int f = f0 + ff;
      if (f < 50) {
        float val = vals[ff] + b2[f];
        smem[FTS + r*52 + f] = val;
        out[row*50 + f] = val;
      }
    }
  }
  __syncthreads();
  // mastery / logits / probs
  if (tid < 64) {
    int r = tid, row = row0 + lrow0 + r;
    float s = 0.f;
    float lg[4] = {bo[0], bo[1], bo[2], bo[3]};
    #pragma unroll
    for (int f = 0; f < 50; ++f) {
      float ft = smem[FTS + r*52 + f];
      s += ft;
      #pragma unroll
      for (int c = 0; c < 4; ++c) lg[c] = fmaf(Wo[c*50 + f], ft, lg[c]);
    }
    out[OUT_MAST + row] = s * (1.f / 50.f);
    float mx = fmaxf(fmaxf(lg[0], lg[1]), fmaxf(lg[2], lg[3]));
    float e0 = __expf(lg[0] - mx), e1 = __expf(lg[1] - mx);
    float e2 = __expf(lg[2] - mx), e3 = __expf(lg[3] - mx);
    float inv = 1.f / (e0 + e1 + e2 + e3);
    #pragma unroll
    for (int c = 0; c < 4; ++c) out[OUT_LOG + row*4 + c] = lg[c];
    out[OUT_PROB + row*4 + 0] = e0 * inv;
    out[OUT_PROB + row*4 + 1] = e1 * inv;
    out[OUT_PROB + row*4 + 2] = e2 * inv;
    out[OUT_PROB + row*4 + 3] = e3 * inv;
  }
}

// ---------------------------------------------------------------- launch ----
// bf16 storage; rd aliases ad. nc = batch chunks (scratch holds one chunk).
static void launch_pipeline(const int* questions, const int* responses,
                            const float* qtab, const float* Wv, const float* bv,
                            const float* keymem, const float* ivm,
                            const float* Wq, const float* bq,
                            const float* Wk, const float* bk,
                            const float* We, const float* be,
                            const float* Wa, const float* ba,
                            const float* W1, const float* b1,
                            const float* W2, const float* b2,
                            const float* Wo, const float* bo,
                            float* ws, float* out, int nc, hipStream_t stream) {
  const int RPC = ROWS / nc;          // rows per chunk
  const int BPC = BATCH / nc;         // batch elems per chunk
  bf16* attn = (bf16*)((char*)ws + (size_t)PREP_FLOATS * 4);
  bf16* er   = attn + (size_t)RPC * 50;
  bf16* ad   = er   + (size_t)RPC * 200;   // rec overwrites with rd in place

  prep_kernel<<<3593, 256, 0, stream>>>(keymem, Wk, bk, Wv, We, Wa, W1, W2, ws);
  for (int c = 0; c < nc; ++c) {
    int row0 = c * RPC;
    attn_kernel<<<RPC/4,  256, 0, stream>>>(questions, qtab, Wq, bq, ws, attn, row0);
    ea_kernel  <<<RPC/32, 256, 0, stream>>>(questions, responses, bv, be, ba, ws, er, ad, row0);
    rec_kernel <<<dim3(BPC, 4), 64, 0, stream>>>(ivm, attn, er, ad);
    mlp_kernel <<<RPC/64, 512, 0, stream>>>(questions, qtab, b1, b2, Wo, bo, ws, ad, out, row0);
  }
}

extern "C" void kernel_launch(void* const* d_in, const int* in_sizes, int n_in,
                              void* d_out, int out_size, void* d_ws, size_t ws_size,
                              hipStream_t stream) {
  const int*   questions = (const int*)d_in[0];
  const int*   responses = (const int*)d_in[1];
  const float* qtab      = (const float*)d_in[2];
  const float* Wv        = (const float*)d_in[3];
  const float* bv        = (const float*)d_in[4];
  const float* keymem    = (const float*)d_in[5];
  const float* ivm       = (const float*)d_in[6];
  const float* Wq        = (const float*)d_in[7];
  const float* bq        = (const float*)d_in[8];
  const float* Wk        = (const float*)d_in[9];
  const float* bk        = (const float*)d_in[10];
  const float* We        = (const float*)d_in[11];
  const float* be        = (const float*)d_in[12];
  const float* Wa        = (const float*)d_in[13];
  const float* ba        = (const float*)d_in[14];
  const float* W1        = (const float*)d_in[15];
  const float* b1        = (const float*)d_in[16];
  const float* W2        = (const float*)d_in[17];
  const float* b2        = (const float*)d_in[18];
  const float* Wo        = (const float*)d_in[19];
  const float* bo        = (const float*)d_in[20];
  float* ws  = (float*)d_ws;
  float* out = (float*)d_out;

  // scratch need: prep + (ROWS/nc) * (50 attn + 200 er + 200 ad/rd) bf16
  const size_t prep_b = (size_t)PREP_FLOATS * 4;
  auto need = [&](int nc) {
    return prep_b + ((size_t)ROWS / nc) * 450 * 2;
  };

  int nc;
  if      (ws_size >= need(1))  nc = 1;   // 234 MB: full batch, 2048-wave rec
  else if (ws_size >= need(2))  nc = 2;   // 119 MB
  else if (ws_size >= need(4))  nc = 4;   // 61 MB
  else if (ws_size >= need(8))  nc = 8;   // 33 MB
  else                          nc = 16;  // 18 MB
  launch_pipeline(questions, responses, qtab, Wv, bv, keymem, ivm,
                  Wq, bq, Wk, bk, We, be, Wa, ba, W1, b1, W2, b2,
                  Wo, bo, ws, out, nc, stream);
}

// Round 9
// 1948.697 us; speedup vs baseline: 1.8549x; 1.2419x over previous
//
#include <hip/hip_runtime.h>
#include <hip/hip_bf16.h>
#include <math.h>

// Problem constants
#define ROWS 256000     // B*S = 512*500
#define BATCH 512

// prep region (float offsets in ws)
#define OFF_TK   0          // tk [50][50] f32
#define OFF_WVT  2512       // WvT [4000][200] f32
#define OFF_WTB  802512     // WTB bf16 [416 cols][224 k]  (We.T|Wa.T, zero-padded)
#define OFF_W1T  882512     // W1T [250][128] f32 (zero-padded u>=100)
#define OFF_W2T  914512     // W2T [100][52]  f32 (zero-padded f>=50)
#define PREP_FLOATS 919712

// output layout (float offsets)
#define OUT_MAST 12800000
#define OUT_LOG  13056000
#define OUT_PROB 14080000

typedef __hip_bfloat16 bf16;
typedef __attribute__((ext_vector_type(8))) short bf16x8;
typedef __attribute__((ext_vector_type(4))) float f32x4;
__device__ inline float ldT(const bf16* p) { return __bfloat162float(*p); }
__device__ inline void stT(bf16* p, float v) { *p = __float2bfloat16(v); }
__device__ inline short bfbits(float v) { __hip_bfloat16 h = __float2bfloat16(v); return *(short*)&h; }

// ---------------------------------------------------------------- prep ----
__global__ __launch_bounds__(256) void prep_kernel(
    const float* __restrict__ keymem, const float* __restrict__ Wk,
    const float* __restrict__ bk, const float* __restrict__ Wv,
    const float* __restrict__ We, const float* __restrict__ Wa,
    const float* __restrict__ W1, const float* __restrict__ W2,
    float* __restrict__ ws) {
  int idx = blockIdx.x * 256 + threadIdx.x;
  if (idx < 2500) {                      // tk[m][k] = sum_l km[l][k]*Wk[m][l] + bk[m]
    int m = idx / 50, k = idx - m * 50;
    float acc = bk[m];
    for (int l = 0; l < 50; ++l) acc = fmaf(keymem[l*50 + k], Wk[m*50 + l], acc);
    ws[OFF_TK + m*50 + k] = acc;
    return;
  }
  idx -= 2500;
  if (idx < 800000) {                    // WvT[j][v] = Wv[v][j]
    int j = idx / 200, v = idx - j * 200;
    ws[OFF_WVT + j*200 + v] = Wv[v*4000 + j];
    return;
  }
  idx -= 800000;
  if (idx < 93184) {                     // WTB bf16 [416][224]
    int col = idx / 224, k = idx - col * 224;
    float val = 0.f;
    if (k < 200 && col < 400)
      val = (col < 200) ? We[col*200 + k] : Wa[(col-200)*200 + k];
    ((bf16*)(ws + OFF_WTB))[idx] = __float2bfloat16(val);
    return;
  }
  idx -= 93184;
  if (idx < 32000) {                     // W1T[j][u], [250][128]
    int j = idx / 128, u = idx - j * 128;
    ws[OFF_W1T + j*128 + u] = (u < 100) ? W1[u*250 + j] : 0.f;
    return;
  }
  idx -= 32000;
  if (idx < 5200) {                      // W2T[j][f], [100][52]
    int j = idx / 52, f = idx - j * 52;
    ws[OFF_W2T + j*52 + f] = (f < 50) ? W2[f*100 + j] : 0.f;
    return;
  }
}

// ---------------------------------------------------------------- attn ----
// wave per (b,t) row; 4 waves per block; attn buffer is chunk-local
__global__ __launch_bounds__(256) void attn_kernel(
    const int* __restrict__ questions, const float* __restrict__ qtab,
    const float* __restrict__ Wq, const float* __restrict__ bq,
    const float* __restrict__ ws, bf16* __restrict__ attn, int row0) {
  __shared__ float qe_s[4][52];
  __shared__ float qu_s[4][52];
  int w = threadIdx.x >> 6;
  int lane = threadIdx.x & 63;
  int lrow = blockIdx.x * 4 + w;
  int row = row0 + lrow;
  int qi = questions[row];
  if (lane < 50) qe_s[w][lane] = qtab[qi*50 + lane];
  __syncthreads();
  if (lane < 50) {
    float acc = bq[lane];
    const float* wq = Wq + lane*50;
    #pragma unroll
    for (int j = 0; j < 50; ++j) acc = fmaf(qe_s[w][j], wq[j], acc);
    qu_s[w][lane] = tanhf(acc);
  }
  __syncthreads();
  float sc = -3.0e38f;
  if (lane < 50) {
    float acc = 0.f;
    const float* tkr = ws + OFF_TK + lane*50;
    #pragma unroll
    for (int k = 0; k < 50; ++k) acc = fmaf(qu_s[w][k], tkr[k], acc);
    sc = acc;
  }
  float mx = sc;
  #pragma unroll
  for (int d = 32; d > 0; d >>= 1) mx = fmaxf(mx, __shfl_xor(mx, d));
  float ex = (lane < 50) ? __expf(sc - mx) : 0.f;
  float sm = ex;
  #pragma unroll
  for (int d = 32; d > 0; d >>= 1) sm += __shfl_xor(sm, d);
  if (lane < 50) stT(&attn[lrow*50 + lane], ex / sm);
}

// ------------------------------------------------------------ erase/add ----
// MFMA version: per block 32 rows; Z[32 x 416] = VE[32 x 224] @ WTB^T
// 4 waves: wid&1 = row-tile (16 rows), wid>>1 = col-half (208 cols = 13 tiles)
__global__ __launch_bounds__(256) void ea_kernel(
    const int* __restrict__ questions, const int* __restrict__ responses,
    const float* __restrict__ bv, const float* __restrict__ be,
    const float* __restrict__ ba, const float* __restrict__ ws,
    bf16* __restrict__ er, bf16* __restrict__ ad, int row0) {
  __shared__ __align__(16) short smem[32*420];   // gather view [32][232], out view [32][420]
  const int tid = threadIdx.x;
  const int lrow0 = blockIdx.x * 32;
  const float* wvt = ws + OFF_WVT;
  const short* wtb = (const short*)(ws + OFF_WTB);

  // ---- gather VE into LDS bf16 [32][232] (k >= 200 zeroed) ----
  for (int i = tid; i < 32*232; i += 256) {
    int r = i / 232, v = i - r*232;
    float acc = 0.f;
    if (v < 200) {
      int row = row0 + lrow0 + r;
      int qi = questions[row];
      acc = bv[v];
      if (qi > 0) {
        int resp = responses[row];
        const float* base = wvt + (qi - 1)*200 + v;
        #pragma unroll
        for (int c = 0; c < 4; ++c) {
          float wgt = 1.f - fabsf((float)(c - resp)) * (1.f/3.f);
          if (wgt > 0.f) acc = fmaf(wgt, base[c*200000], acc);
        }
      }
    }
    smem[r*232 + v] = bfbits(acc);
  }
  __syncthreads();

  // ---- MFMA GEMM ----
  const int lane = tid & 63, wid = tid >> 6;
  const int rw = wid & 1, cw = wid >> 1;
  const int arow = rw*16 + (lane & 15);
  const int kb = (lane >> 4) * 8;
  f32x4 acc[13];
  #pragma unroll
  for (int t = 0; t < 13; ++t) acc[t] = (f32x4){0.f, 0.f, 0.f, 0.f};
  const short* bbase = wtb + (size_t)(cw*208 + (lane & 15))*224 + kb;
  const short* abase = &smem[arow*232 + kb];
  #pragma unroll
  for (int ks = 0; ks < 7; ++ks) {
    bf16x8 a = *(const bf16x8*)(abase + ks*32);
    #pragma unroll
    for (int t = 0; t < 13; ++t) {
      bf16x8 b = *(const bf16x8*)(bbase + t*(16*224) + ks*32);
      acc[t] = __builtin_amdgcn_mfma_f32_16x16x32_bf16(a, b, acc[t], 0, 0, 0);
    }
  }
  __syncthreads();   // all waves done reading VE before LDS reuse

  // ---- bias + activation, staged to LDS out [32][420] ----
  const int orow = rw*16 + (lane >> 4)*4;
  #pragma unroll
  for (int t = 0; t < 13; ++t) {
    int col = cw*208 + t*16 + (lane & 15);
    float bias = (col < 200) ? be[col] : ((col < 400) ? ba[col - 200] : 0.f);
    #pragma unroll
    for (int r = 0; r < 4; ++r) {
      float z = acc[t][r] + bias;
      float y = (col < 200) ? 1.f/(1.f + __expf(-z)) : tanhf(z);
      smem[(orow + r)*420 + col] = bfbits(y);
    }
  }
  __syncthreads();

  // ---- coalesced copy out ----
  for (int i = tid; i < 12800; i += 256) {
    int r = i / 400, c = i - r*400;
    short val = smem[r*420 + c];
    if (c < 200) ((short*)er)[(lrow0 + r)*200 + c]         = val;
    else         ((short*)ad)[(lrow0 + r)*200 + (c - 200)] = val;
  }
}

// ------------------------------------------------------------ recurrence ----
// grid = (batch_per_chunk, 4 v-groups); ONE wave per block, no LDS, no barriers.
// Lane l (<50) owns column v = vg*50+l; vm[50] in registers.
// attn broadcast via v_readlane. Unroll-4 circular buffer => loads issued 3
// iterations before use. rd written IN PLACE over ad (ad[t] dead after load).
__device__ inline float lane_bcast(float x, int m) {
  return __uint_as_float(__builtin_amdgcn_readlane(__float_as_uint(x), m));
}

__global__ __launch_bounds__(64) void rec_kernel(
    const float* __restrict__ ivm, const bf16* __restrict__ attn,
    const bf16* __restrict__ er, bf16* __restrict__ ad_rd) {
  const int lane = threadIdx.x;            // 0..63
  const int b    = blockIdx.x;             // chunk-local batch element
  const int vg   = blockIdx.y;             // 0..3
  const int v    = vg * 50 + lane;         // valid if lane<50
  const bool av  = lane < 50;
  const long base = (long)b * 500;

  float vm[50];
  #pragma unroll
  for (int m = 0; m < 50; ++m) vm[m] = 0.f;
  if (av) {
    #pragma unroll
    for (int m = 0; m < 50; ++m) vm[m] = ivm[m*200 + v];
  }

  const bf16* erp = er    + base*200 + v;
  bf16*       adp = ad_rd + base*200 + v;
  const bf16* atp = attn  + base*50  + lane;

  float eb[4], ab[4], tb[4];
  #pragma unroll
  for (int j = 0; j < 4; ++j) { eb[j] = 0.f; ab[j] = 0.f; tb[j] = 0.f; }
  if (av) {
    #pragma unroll
    for (int j = 0; j < 3; ++j) {
      eb[j] = ldT(erp + j*200);
      ab[j] = ldT(adp + j*200);
      tb[j] = ldT(atp + j*50);
    }
  }

  for (int t4 = 0; t4 < 124; ++t4) {
    #pragma unroll
    for (int j = 0; j < 4; ++j) {
      const int t  = t4*4 + j;
      const int cs = j;
      const int ls = (j + 3) & 3;
      if (av) {
        eb[ls] = ldT(erp + (t+3)*200);
        ab[ls] = ldT(adp + (t+3)*200);
        tb[ls] = ldT(atp + (t+3)*50);
      }
      float e0 = eb[cs], a0 = ab[cs], t0 = tb[cs];
      float r0 = 0.f, r1 = 0.f, r2 = 0.f, r3 = 0.f;
      #pragma unroll
      for (int m = 0; m < 48; m += 4) {
        float am0 = lane_bcast(t0, m);
        r0 = fmaf(am0, vm[m], r0);
        vm[m] = fmaf(am0, fmaf(-vm[m], e0, a0), vm[m]);
        float am1 = lane_bcast(t0, m + 1);
        r1 = fmaf(am1, vm[m+1], r1);
        vm[m+1] = fmaf(am1, fmaf(-vm[m+1], e0, a0), vm[m+1]);
        float am2 = lane_bcast(t0, m + 2);
        r2 = fmaf(am2, vm[m+2], r2);
        vm[m+2] = fmaf(am2, fmaf(-vm[m+2], e0, a0), vm[m+2]);
        float am3 = lane_bcast(t0, m + 3);
        r3 = fmaf(am3, vm[m+3], r3);
        vm[m+3] = fmaf(am3, fmaf(-vm[m+3], e0, a0), vm[m+3]);
      }
      {
        float am0 = lane_bcast(t0, 48);
        r0 = fmaf(am0, vm[48], r0);
        vm[48] = fmaf(am0, fmaf(-vm[48], e0, a0), vm[48]);
        float am1 = lane_bcast(t0, 49);
        r1 = fmaf(am1, vm[49], r1);
        vm[49] = fmaf(am1, fmaf(-vm[49], e0, a0), vm[49]);
      }
      if (av) stT(adp + t*200, (r0 + r1) + (r2 + r3));
    }
  }
  #pragma unroll
  for (int j = 0; j < 4; ++j) {
    const int t  = 496 + j;
    const int cs = j;
    const int ls = (j + 3) & 3;
    if (j == 0 && av) {
      eb[ls] = ldT(erp + 499*200);
      ab[ls] = ldT(adp + 499*200);
      tb[ls] = ldT(atp + 499*50);
    }
    float e0 = eb[cs], a0 = ab[cs], t0 = tb[cs];
    float r0 = 0.f, r1 = 0.f, r2 = 0.f, r3 = 0.f;
    #pragma unroll
    for (int m = 0; m < 48; m += 4) {
      float am0 = lane_bcast(t0, m);
      r0 = fmaf(am0, vm[m], r0);
      vm[m] = fmaf(am0, fmaf(-vm[m], e0, a0), vm[m]);
      float am1 = lane_bcast(t0, m + 1);
      r1 = fmaf(am1, vm[m+1], r1);
      vm[m+1] = fmaf(am1, fmaf(-vm[m+1], e0, a0), vm[m+1]);
      float am2 = lane_bcast(t0, m + 2);
      r2 = fmaf(am2, vm[m+2], r2);
      vm[m+2] = fmaf(am2, fmaf(-vm[m+2], e0, a0), vm[m+2]);
      float am3 = lane_bcast(t0, m + 3);
      r3 = fmaf(am3, vm[m+3], r3);
      vm[m+3] = fmaf(am3, fmaf(-vm[m+3], e0, a0), vm[m+3]);
    }
    {
      float am0 = lane_bcast(t0, 48);
      r0 = fmaf(am0, vm[48], r0);
      vm[48] = fmaf(am0, fmaf(-vm[48], e0, a0), vm[48]);
      float am1 = lane_bcast(t0, 49);
      r1 = fmaf(am1, vm[49], r1);
      vm[49] = fmaf(am1, fmaf(-vm[49], e0, a0), vm[49]);
    }
    if (av) stT(adp + t*200, (r0 + r1) + (r2 + r3));
  }
}

// ---------------------------------------------------------------- MLP ----
// 64 rows/block, 512 threads; GEMM1 [64x128] K=250 (4x4 reg tile), GEMM2 [64x52] K=100
#define W1S 0
#define HS  6400
#define Z1S 0
#define W2S 6656
#define FTS 11856

__global__ __launch_bounds__(512) void mlp_kernel(
    const int* __restrict__ questions, const float* __restrict__ qtab,
    const float* __restrict__ b1, const float* __restrict__ b2,
    const float* __restrict__ Wo, const float* __restrict__ bo,
    const float* __restrict__ ws, const bf16* __restrict__ rd,
    float* __restrict__ out, int row0) {
  __shared__ __align__(16) float smem[15184];
  int tid = threadIdx.x;
  int lrow0 = blockIdx.x * 64;
  const float* w1t = ws + OFF_W1T;
  int ug = tid & 31, rg = tid >> 5;
  int u0 = ug * 4, r0 = rg * 4;
  float acc[4][4];
  #pragma unroll
  for (int i = 0; i < 4; ++i)
    #pragma unroll
    for (int j = 0; j < 4; ++j) acc[i][j] = 0.f;

  for (int kt = 0; kt < 5; ++kt) {
    int j0 = kt * 50;
    for (int i = tid; i < 6400; i += 512)        // W1T tile [50][128]
      smem[W1S + i] = w1t[j0*128 + i];
    for (int i = tid; i < 3200; i += 512) {      // h tile [64][50]
      int r = i / 50, jj = i - r * 50;
      int lrow = lrow0 + r;
      int j = j0 + jj;
      float hv;
      if (j < 200) hv = ldT(&rd[lrow*200 + j]);
      else         hv = qtab[questions[row0 + lrow]*50 + (j - 200)];
      smem[HS + r*50 + jj] = hv;
    }
    __syncthreads();
    #pragma unroll 2
    for (int jj = 0; jj < 50; ++jj) {
      float4 wv = *(const float4*)&smem[W1S + jj*128 + u0];
      #pragma unroll
      for (int rr = 0; rr < 4; ++rr) {
        float h = smem[HS + (r0 + rr)*50 + jj];
        acc[rr][0] = fmaf(h, wv.x, acc[rr][0]);
        acc[rr][1] = fmaf(h, wv.y, acc[rr][1]);
        acc[rr][2] = fmaf(h, wv.z, acc[rr][2]);
        acc[rr][3] = fmaf(h, wv.w, acc[rr][3]);
      }
    }
    __syncthreads();
  }
  // z1 = relu(acc + b1) into LDS [64][104]
  if (u0 < 100) {
    #pragma unroll
    for (int uu = 0; uu < 4; ++uu) {
      int u = u0 + uu;
      float bb = b1[u];
      #pragma unroll
      for (int rr = 0; rr < 4; ++rr) {
        float z = acc[rr][uu] + bb;
        smem[Z1S + (r0 + rr)*104 + u] = fmaxf(z, 0.f);
      }
    }
  }
  for (int i = tid; i < 5200; i += 512)          // W2T [100][52]
    smem[W2S + i] = ws[OFF_W2T + i];
  __syncthreads();
  // GEMM2: feat [64][50]
  for (int i = tid; i < 832; i += 512) {
    int r = i / 13, fg = i - r * 13;
    int f0 = fg * 4;
    float a0 = 0.f, a1 = 0.f, a2 = 0.f, a3 = 0.f;
    #pragma unroll 4
    for (int j = 0; j < 100; ++j) {
      float z = smem[Z1S + r*104 + j];
      float4 wv = *(const float4*)&smem[W2S + j*52 + f0];
      a0 = fmaf(z, wv.x, a0);
      a1 = fmaf(z, wv.y, a1);
      a2 = fmaf(z, wv.z, a2);
      a3 = fmaf(z, wv.w, a3);
    }
    int row = row0 + lrow0 + r;
    float vals[4] = {a0, a1, a2, a3};
    #pragma unroll
    for (int ff = 0; ff < 4; ++ff) {
      int f = f0 + ff;
      if (f < 50) {
        float val = vals[ff] + b2[f];
        smem[FTS + r*52 + f] = val;
        out[row*50 + f] = val;
      }
    }
  }
  __syncthreads();
  // mastery / logits / probs
  if (tid < 64) {
    int r = tid, row = row0 + lrow0 + r;
    float s = 0.f;
    float lg[4] = {bo[0], bo[1], bo[2], bo[3]};
    #pragma unroll
    for (int f = 0; f < 50; ++f) {
      float ft = smem[FTS + r*52 + f];
      s += ft;
      #pragma unroll
      for (int c = 0; c < 4; ++c) lg[c] = fmaf(Wo[c*50 + f], ft, lg[c]);
    }
    out[OUT_MAST + row] = s * (1.f / 50.f);
    float mx = fmaxf(fmaxf(lg[0], lg[1]), fmaxf(lg[2], lg[3]));
    float e0 = __expf(lg[0] - mx), e1 = __expf(lg[1] - mx);
    float e2 = __expf(lg[2] - mx), e3 = __expf(lg[3] - mx);
    float inv = 1.f / (e0 + e1 + e2 + e3);
    #pragma unroll
    for (int c = 0; c < 4; ++c) out[OUT_LOG + row*4 + c] = lg[c];
    out[OUT_PROB + row*4 + 0] = e0 * inv;
    out[OUT_PROB + row*4 + 1] = e1 * inv;
    out[OUT_PROB + row*4 + 2] = e2 * inv;
    out[OUT_PROB + row*4 + 3] = e3 * inv;
  }
}

// ---------------------------------------------------------------- launch ----
static void launch_pipeline(const int* questions, const int* responses,
                            const float* qtab, const float* Wv, const float* bv,
                            const float* keymem, const float* ivm,
                            const float* Wq, const float* bq,
                            const float* Wk, const float* bk,
                            const float* We, const float* be,
                            const float* Wa, const float* ba,
                            const float* W1, const float* b1,
                            const float* W2, const float* b2,
                            const float* Wo, const float* bo,
                            float* ws, float* out, int nc, hipStream_t stream) {
  const int RPC = ROWS / nc;          // rows per chunk
  const int BPC = BATCH / nc;         // batch elems per chunk
  bf16* attn = (bf16*)((char*)ws + (size_t)PREP_FLOATS * 4);
  bf16* er   = attn + (size_t)RPC * 50;
  bf16* ad   = er   + (size_t)RPC * 200;   // rec overwrites with rd in place

  prep_kernel<<<3645, 256, 0, stream>>>(keymem, Wk, bk, Wv, We, Wa, W1, W2, ws);
  for (int c = 0; c < nc; ++c) {
    int row0 = c * RPC;
    attn_kernel<<<RPC/4,  256, 0, stream>>>(questions, qtab, Wq, bq, ws, attn, row0);
    ea_kernel  <<<RPC/32, 256, 0, stream>>>(questions, responses, bv, be, ba, ws, er, ad, row0);
    rec_kernel <<<dim3(BPC, 4), 64, 0, stream>>>(ivm, attn, er, ad);
    mlp_kernel <<<RPC/64, 512, 0, stream>>>(questions, qtab, b1, b2, Wo, bo, ws, ad, out, row0);
  }
}

extern "C" void kernel_launch(void* const* d_in, const int* in_sizes, int n_in,
                              void* d_out, int out_size, void* d_ws, size_t ws_size,
                              hipStream_t stream) {
  const int*   questions = (const int*)d_in[0];
  const int*   responses = (const int*)d_in[1];
  const float* qtab      = (const float*)d_in[2];
  const float* Wv        = (const float*)d_in[3];
  const float* bv        = (const float*)d_in[4];
  const float* keymem    = (const float*)d_in[5];
  const float* ivm       = (const float*)d_in[6];
  const float* Wq        = (const float*)d_in[7];
  const float* bq        = (const float*)d_in[8];
  const float* Wk        = (const float*)d_in[9];
  const float* bk        = (const float*)d_in[10];
  const float* We        = (const float*)d_in[11];
  const float* be        = (const float*)d_in[12];
  const float* Wa        = (const float*)d_in[13];
  const float* ba        = (const float*)d_in[14];
  const float* W1        = (const float*)d_in[15];
  const float* b1        = (const float*)d_in[16];
  const float* W2        = (const float*)d_in[17];
  const float* b2        = (const float*)d_in[18];
  const float* Wo        = (const float*)d_in[19];
  const float* bo        = (const float*)d_in[20];
  float* ws  = (float*)d_ws;
  float* out = (float*)d_out;

  const size_t prep_b = (size_t)PREP_FLOATS * 4;
  auto need = [&](int nc) {
    return prep_b + ((size_t)ROWS / nc) * 450 * 2;
  };

  int nc;
  if      (ws_size >= need(1))  nc = 1;   // 234 MB: full batch
  else if (ws_size >= need(2))  nc = 2;
  else if (ws_size >= need(4))  nc = 4;
  else if (ws_size >= need(8))  nc = 8;
  else                          nc = 16;
  launch_pipeline(questions, responses, qtab, Wv, bv, keymem, ivm,
                  Wq, bq, Wk, bk, We, be, Wa, ba, W1, b1, W2, b2,
                  Wo, bo, ws, out, nc, stream);
}

// Round 10
// 1942.664 us; speedup vs baseline: 1.8606x; 1.0031x over previous
//
#include <hip/hip_runtime.h>
#include <hip/hip_bf16.h>
#include <math.h>

// Problem constants
#define ROWS 256000     // B*S = 512*500
#define BATCH 512

// prep region (float offsets in ws)
#define OFF_TK   0          // tk [50][50] f32
#define OFF_WVT  2512       // WvT [4000][200] f32
#define OFF_WTB  802512     // WTB bf16 [416 cols][224 k]  (We.T|Wa.T, zero-padded)
#define OFF_W1T  882512     // W1T [250][128] f32 (zero-padded u>=100)
#define OFF_W2T  914512     // W2T [100][52]  f32 (zero-padded f>=50)
#define PREP_FLOATS 919712

// output layout (float offsets)
#define OUT_MAST 12800000
#define OUT_LOG  13056000
#define OUT_PROB 14080000

typedef __hip_bfloat16 bf16;
typedef __attribute__((ext_vector_type(8))) short bf16x8;
typedef __attribute__((ext_vector_type(4))) float f32x4;
__device__ inline float ldT(const bf16* p) { return __bfloat162float(*p); }
__device__ inline void stT(bf16* p, float v) { *p = __float2bfloat16(v); }
__device__ inline short bfbits(float v) { __hip_bfloat16 h = __float2bfloat16(v); return *(short*)&h; }

// ---------------------------------------------------------------- prep ----
__global__ __launch_bounds__(256) void prep_kernel(
    const float* __restrict__ keymem, const float* __restrict__ Wk,
    const float* __restrict__ bk, const float* __restrict__ Wv,
    const float* __restrict__ We, const float* __restrict__ Wa,
    const float* __restrict__ W1, const float* __restrict__ W2,
    float* __restrict__ ws) {
  int idx = blockIdx.x * 256 + threadIdx.x;
  if (idx < 2500) {                      // tk[m][k] = sum_l km[l][k]*Wk[m][l] + bk[m]
    int m = idx / 50, k = idx - m * 50;
    float acc = bk[m];
    for (int l = 0; l < 50; ++l) acc = fmaf(keymem[l*50 + k], Wk[m*50 + l], acc);
    ws[OFF_TK + m*50 + k] = acc;
    return;
  }
  idx -= 2500;
  if (idx < 800000) {                    // WvT[j][v] = Wv[v][j]
    int j = idx / 200, v = idx - j * 200;
    ws[OFF_WVT + j*200 + v] = Wv[v*4000 + j];
    return;
  }
  idx -= 800000;
  if (idx < 93184) {                     // WTB bf16 [416][224]
    int col = idx / 224, k = idx - col * 224;
    float val = 0.f;
    if (k < 200 && col < 400)
      val = (col < 200) ? We[col*200 + k] : Wa[(col-200)*200 + k];
    ((bf16*)(ws + OFF_WTB))[idx] = __float2bfloat16(val);
    return;
  }
  idx -= 93184;
  if (idx < 32000) {                     // W1T[j][u], [250][128]
    int j = idx / 128, u = idx - j * 128;
    ws[OFF_W1T + j*128 + u] = (u < 100) ? W1[u*250 + j] : 0.f;
    return;
  }
  idx -= 32000;
  if (idx < 5200) {                      // W2T[j][f], [100][52]
    int j = idx / 52, f = idx - j * 52;
    ws[OFF_W2T + j*52 + f] = (f < 50) ? W2[f*100 + j] : 0.f;
    return;
  }
}

// ---------------------------------------------------------------- attn ----
// wave per (b,t) row; 4 waves per block; attn buffer is chunk-local
__global__ __launch_bounds__(256) void attn_kernel(
    const int* __restrict__ questions, const float* __restrict__ qtab,
    const float* __restrict__ Wq, const float* __restrict__ bq,
    const float* __restrict__ ws, bf16* __restrict__ attn, int row0) {
  __shared__ float qe_s[4][52];
  __shared__ float qu_s[4][52];
  int w = threadIdx.x >> 6;
  int lane = threadIdx.x & 63;
  int lrow = blockIdx.x * 4 + w;
  int row = row0 + lrow;
  int qi = questions[row];
  if (lane < 50) qe_s[w][lane] = qtab[qi*50 + lane];
  __syncthreads();
  if (lane < 50) {
    float acc = bq[lane];
    const float* wq = Wq + lane*50;
    #pragma unroll
    for (int j = 0; j < 50; ++j) acc = fmaf(qe_s[w][j], wq[j], acc);
    qu_s[w][lane] = tanhf(acc);
  }
  __syncthreads();
  float sc = -3.0e38f;
  if (lane < 50) {
    float acc = 0.f;
    const float* tkr = ws + OFF_TK + lane*50;
    #pragma unroll
    for (int k = 0; k < 50; ++k) acc = fmaf(qu_s[w][k], tkr[k], acc);
    sc = acc;
  }
  float mx = sc;
  #pragma unroll
  for (int d = 32; d > 0; d >>= 1) mx = fmaxf(mx, __shfl_xor(mx, d));
  float ex = (lane < 50) ? __expf(sc - mx) : 0.f;
  float sm = ex;
  #pragma unroll
  for (int d = 32; d > 0; d >>= 1) sm += __shfl_xor(sm, d);
  if (lane < 50) stT(&attn[lrow*50 + lane], ex / sm);
}

// ------------------------------------------------------------ erase/add ----
// MFMA version: per block 32 rows; Z[32 x 416] = VE[32 x 224] @ WTB^T
// 4 waves: wid&1 = row-tile (16 rows), wid>>1 = col-half (208 cols = 13 tiles)
// B-loads BATCHED into registers per K-step (one waitcnt per ks, not 13).
__global__ __launch_bounds__(256) void ea_kernel(
    const int* __restrict__ questions, const int* __restrict__ responses,
    const float* __restrict__ bv, const float* __restrict__ be,
    const float* __restrict__ ba, const float* __restrict__ ws,
    bf16* __restrict__ er, bf16* __restrict__ ad, int row0) {
  __shared__ __align__(16) short smem[32*420];   // gather view [32][232], out view [32][420]
  const int tid = threadIdx.x;
  const int lrow0 = blockIdx.x * 32;
  const float* wvt = ws + OFF_WVT;
  const short* wtb = (const short*)(ws + OFF_WTB);

  // ---- gather VE into LDS bf16 [32][232] (k >= 200 zeroed) ----
  for (int i = tid; i < 32*232; i += 256) {
    int r = i / 232, v = i - r*232;
    float acc = 0.f;
    if (v < 200) {
      int row = row0 + lrow0 + r;
      int qi = questions[row];
      acc = bv[v];
      if (qi > 0) {
        int resp = responses[row];
        const float* base = wvt + (qi - 1)*200 + v;
        #pragma unroll
        for (int c = 0; c < 4; ++c) {
          float wgt = 1.f - fabsf((float)(c - resp)) * (1.f/3.f);
          if (wgt > 0.f) acc = fmaf(wgt, base[c*200000], acc);
        }
      }
    }
    smem[r*232 + v] = bfbits(acc);
  }
  __syncthreads();

  // ---- MFMA GEMM (B-loads batched per K-step) ----
  const int lane = tid & 63, wid = tid >> 6;
  const int rw = wid & 1, cw = wid >> 1;
  const int arow = rw*16 + (lane & 15);
  const int kb = (lane >> 4) * 8;
  f32x4 acc[13];
  #pragma unroll
  for (int t = 0; t < 13; ++t) acc[t] = (f32x4){0.f, 0.f, 0.f, 0.f};
  const short* bbase = wtb + (size_t)(cw*208 + (lane & 15))*224 + kb;
  const short* abase = &smem[arow*232 + kb];
  #pragma unroll
  for (int ks = 0; ks < 7; ++ks) {
    bf16x8 breg[13];
    #pragma unroll
    for (int t = 0; t < 13; ++t)
      breg[t] = *(const bf16x8*)(bbase + t*(16*224) + ks*32);
    bf16x8 a = *(const bf16x8*)(abase + ks*32);
    #pragma unroll
    for (int t = 0; t < 13; ++t)
      acc[t] = __builtin_amdgcn_mfma_f32_16x16x32_bf16(a, breg[t], acc[t], 0, 0, 0);
  }
  __syncthreads();   // all waves done reading VE before LDS reuse

  // ---- bias + activation, staged to LDS out [32][420] ----
  const int orow = rw*16 + (lane >> 4)*4;
  #pragma unroll
  for (int t = 0; t < 13; ++t) {
    int col = cw*208 + t*16 + (lane & 15);
    float bias = (col < 200) ? be[col] : ((col < 400) ? ba[col - 200] : 0.f);
    #pragma unroll
    for (int r = 0; r < 4; ++r) {
      float z = acc[t][r] + bias;
      float y = (col < 200) ? 1.f/(1.f + __expf(-z)) : tanhf(z);
      smem[(orow + r)*420 + col] = bfbits(y);
    }
  }
  __syncthreads();

  // ---- coalesced copy out ----
  for (int i = tid; i < 12800; i += 256) {
    int r = i / 400, c = i - r*400;
    short val = smem[r*420 + c];
    if (c < 200) ((short*)er)[(lrow0 + r)*200 + c]         = val;
    else         ((short*)ad)[(lrow0 + r)*200 + (c - 200)] = val;
  }
}

// ------------------------------------------------------------ recurrence ----
// grid = (batch_per_chunk, 4 v-groups); ONE wave per block, no LDS, no barriers.
__device__ inline float lane_bcast(float x, int m) {
  return __uint_as_float(__builtin_amdgcn_readlane(__float_as_uint(x), m));
}

__global__ __launch_bounds__(64) void rec_kernel(
    const float* __restrict__ ivm, const bf16* __restrict__ attn,
    const bf16* __restrict__ er, bf16* __restrict__ ad_rd) {
  const int lane = threadIdx.x;            // 0..63
  const int b    = blockIdx.x;             // chunk-local batch element
  const int vg   = blockIdx.y;             // 0..3
  const int v    = vg * 50 + lane;         // valid if lane<50
  const bool av  = lane < 50;
  const long base = (long)b * 500;

  float vm[50];
  #pragma unroll
  for (int m = 0; m < 50; ++m) vm[m] = 0.f;
  if (av) {
    #pragma unroll
    for (int m = 0; m < 50; ++m) vm[m] = ivm[m*200 + v];
  }

  const bf16* erp = er    + base*200 + v;
  bf16*       adp = ad_rd + base*200 + v;
  const bf16* atp = attn  + base*50  + lane;

  float eb[4], ab[4], tb[4];
  #pragma unroll
  for (int j = 0; j < 4; ++j) { eb[j] = 0.f; ab[j] = 0.f; tb[j] = 0.f; }
  if (av) {
    #pragma unroll
    for (int j = 0; j < 3; ++j) {
      eb[j] = ldT(erp + j*200);
      ab[j] = ldT(adp + j*200);
      tb[j] = ldT(atp + j*50);
    }
  }

  for (int t4 = 0; t4 < 124; ++t4) {
    #pragma unroll
    for (int j = 0; j < 4; ++j) {
      const int t  = t4*4 + j;
      const int cs = j;
      const int ls = (j + 3) & 3;
      if (av) {
        eb[ls] = ldT(erp + (t+3)*200);
        ab[ls] = ldT(adp + (t+3)*200);
        tb[ls] = ldT(atp + (t+3)*50);
      }
      float e0 = eb[cs], a0 = ab[cs], t0 = tb[cs];
      float r0 = 0.f, r1 = 0.f, r2 = 0.f, r3 = 0.f;
      #pragma unroll
      for (int m = 0; m < 48; m += 4) {
        float am0 = lane_bcast(t0, m);
        r0 = fmaf(am0, vm[m], r0);
        vm[m] = fmaf(am0, fmaf(-vm[m], e0, a0), vm[m]);
        float am1 = lane_bcast(t0, m + 1);
        r1 = fmaf(am1, vm[m+1], r1);
        vm[m+1] = fmaf(am1, fmaf(-vm[m+1], e0, a0), vm[m+1]);
        float am2 = lane_bcast(t0, m + 2);
        r2 = fmaf(am2, vm[m+2], r2);
        vm[m+2] = fmaf(am2, fmaf(-vm[m+2], e0, a0), vm[m+2]);
        float am3 = lane_bcast(t0, m + 3);
        r3 = fmaf(am3, vm[m+3], r3);
        vm[m+3] = fmaf(am3, fmaf(-vm[m+3], e0, a0), vm[m+3]);
      }
      {
        float am0 = lane_bcast(t0, 48);
        r0 = fmaf(am0, vm[48], r0);
        vm[48] = fmaf(am0, fmaf(-vm[48], e0, a0), vm[48]);
        float am1 = lane_bcast(t0, 49);
        r1 = fmaf(am1, vm[49], r1);
        vm[49] = fmaf(am1, fmaf(-vm[49], e0, a0), vm[49]);
      }
      if (av) stT(adp + t*200, (r0 + r1) + (r2 + r3));
    }
  }
  #pragma unroll
  for (int j = 0; j < 4; ++j) {
    const int t  = 496 + j;
    const int cs = j;
    const int ls = (j + 3) & 3;
    if (j == 0 && av) {
      eb[ls] = ldT(erp + 499*200);
      ab[ls] = ldT(adp + 499*200);
      tb[ls] = ldT(atp + 499*50);
    }
    float e0 = eb[cs], a0 = ab[cs], t0 = tb[cs];
    float r0 = 0.f, r1 = 0.f, r2 = 0.f, r3 = 0.f;
    #pragma unroll
    for (int m = 0; m < 48; m += 4) {
      float am0 = lane_bcast(t0, m);
      r0 = fmaf(am0, vm[m], r0);
      vm[m] = fmaf(am0, fmaf(-vm[m], e0, a0), vm[m]);
      float am1 = lane_bcast(t0, m + 1);
      r1 = fmaf(am1, vm[m+1], r1);
      vm[m+1] = fmaf(am1, fmaf(-vm[m+1], e0, a0), vm[m+1]);
      float am2 = lane_bcast(t0, m + 2);
      r2 = fmaf(am2, vm[m+2], r2);
      vm[m+2] = fmaf(am2, fmaf(-vm[m+2], e0, a0), vm[m+2]);
      float am3 = lane_bcast(t0, m + 3);
      r3 = fmaf(am3, vm[m+3], r3);
      vm[m+3] = fmaf(am3, fmaf(-vm[m+3], e0, a0), vm[m+3]);
    }
    {
      float am0 = lane_bcast(t0, 48);
      r0 = fmaf(am0, vm[48], r0);
      vm[48] = fmaf(am0, fmaf(-vm[48], e0, a0), vm[48]);
      float am1 = lane_bcast(t0, 49);
      r1 = fmaf(am1, vm[49], r1);
      vm[49] = fmaf(am1, fmaf(-vm[49], e0, a0), vm[49]);
    }
    if (av) stT(adp + t*200, (r0 + r1) + (r2 + r3));
  }
}

// ---------------------------------------------------------------- MLP ----
// 64 rows/block, 512 threads; GEMM1 [64x128] K=250 (4x4 reg tile), GEMM2 [64x52] K=100
#define W1S 0
#define HS  6400
#define Z1S 0
#define W2S 6656
#define FTS 11856

__global__ __launch_bounds__(512) void mlp_kernel(
    const int* __restrict__ questions, const float* __restrict__ qtab,
    const float* __restrict__ b1, const float* __restrict__ b2,
    const float* __restrict__ Wo, const float* __restrict__ bo,
    const float* __restrict__ ws, const bf16* __restrict__ rd,
    float* __restrict__ out, int row0) {
  __shared__ __align__(16) float smem[15184];
  int tid = threadIdx.x;
  int lrow0 = blockIdx.x * 64;
  const float* w1t = ws + OFF_W1T;
  int ug = tid & 31, rg = tid >> 5;
  int u0 = ug * 4, r0 = rg * 4;
  float acc[4][4];
  #pragma unroll
  for (int i = 0; i < 4; ++i)
    #pragma unroll
    for (int j = 0; j < 4; ++j) acc[i][j] = 0.f;

  for (int kt = 0; kt < 5; ++kt) {
    int j0 = kt * 50;
    for (int i = tid; i < 6400; i += 512)        // W1T tile [50][128]
      smem[W1S + i] = w1t[j0*128 + i];
    for (int i = tid; i < 3200; i += 512) {      // h tile [64][50]
      int r = i / 50, jj = i - r * 50;
      int lrow = lrow0 + r;
      int j = j0 + jj;
      float hv;
      if (j < 200) hv = ldT(&rd[lrow*200 + j]);
      else         hv = qtab[questions[row0 + lrow]*50 + (j - 200)];
      smem[HS + r*50 + jj] = hv;
    }
    __syncthreads();
    #pragma unroll 2
    for (int jj = 0; jj < 50; ++jj) {
      float4 wv = *(const float4*)&smem[W1S + jj*128 + u0];
      #pragma unroll
      for (int rr = 0; rr < 4; ++rr) {
        float h = smem[HS + (r0 + rr)*50 + jj];
        acc[rr][0] = fmaf(h, wv.x, acc[rr][0]);
        acc[rr][1] = fmaf(h, wv.y, acc[rr][1]);
        acc[rr][2] = fmaf(h, wv.z, acc[rr][2]);
        acc[rr][3] = fmaf(h, wv.w, acc[rr][3]);
      }
    }
    __syncthreads();
  }
  // z1 = relu(acc + b1) into LDS [64][104]
  if (u0 < 100) {
    #pragma unroll
    for (int uu = 0; uu < 4; ++uu) {
      int u = u0 + uu;
      float bb = b1[u];
      #pragma unroll
      for (int rr = 0; rr < 4; ++rr) {
        float z = acc[rr][uu] + bb;
        smem[Z1S + (r0 + rr)*104 + u] = fmaxf(z, 0.f);
      }
    }
  }
  for (int i = tid; i < 5200; i += 512)          // W2T [100][52]
    smem[W2S + i] = ws[OFF_W2T + i];
  __syncthreads();
  // GEMM2: feat [64][50]
  for (int i = tid; i < 832; i += 512) {
    int r = i / 13, fg = i - r * 13;
    int f0 = fg * 4;
    float a0 = 0.f, a1 = 0.f, a2 = 0.f, a3 = 0.f;
    #pragma unroll 4
    for (int j = 0; j < 100; ++j) {
      float z = smem[Z1S + r*104 + j];
      float4 wv = *(const float4*)&smem[W2S + j*52 + f0];
      a0 = fmaf(z, wv.x, a0);
      a1 = fmaf(z, wv.y, a1);
      a2 = fmaf(z, wv.z, a2);
      a3 = fmaf(z, wv.w, a3);
    }
    int row = row0 + lrow0 + r;
    float vals[4] = {a0, a1, a2, a3};
    #pragma unroll
    for (int ff = 0; ff < 4; ++ff) {
      int f = f0 + ff;
      if (f < 50) {
        float val = vals[ff] + b2[f];
        smem[FTS + r*52 + f] = val;
        out[row*50 + f] = val;
      }
    }
  }
  __syncthreads();
  // mastery / logits / probs
  if (tid < 64) {
    int r = tid, row = row0 + lrow0 + r;
    float s = 0.f;
    float lg[4] = {bo[0], bo[1], bo[2], bo[3]};
    #pragma unroll
    for (int f = 0; f < 50; ++f) {
      float ft = smem[FTS + r*52 + f];
      s += ft;
      #pragma unroll
      for (int c = 0; c < 4; ++c) lg[c] = fmaf(Wo[c*50 + f], ft, lg[c]);
    }
    out[OUT_MAST + row] = s * (1.f / 50.f);
    float mx = fmaxf(fmaxf(lg[0], lg[1]), fmaxf(lg[2], lg[3]));
    float e0 = __expf(lg[0] - mx), e1 = __expf(lg[1] - mx);
    float e2 = __expf(lg[2] - mx), e3 = __expf(lg[3] - mx);
    float inv = 1.f / (e0 + e1 + e2 + e3);
    #pragma unroll
    for (int c = 0; c < 4; ++c) out[OUT_LOG + row*4 + c] = lg[c];
    out[OUT_PROB + row*4 + 0] = e0 * inv;
    out[OUT_PROB + row*4 + 1] = e1 * inv;
    out[OUT_PROB + row*4 + 2] = e2 * inv;
    out[OUT_PROB + row*4 + 3] = e3 * inv;
  }
}

// ---------------------------------------------------------------- launch ----
static void launch_pipeline(const int* questions, const int* responses,
                            const float* qtab, const float* Wv, const float* bv,
                            const float* keymem, const float* ivm,
                            const float* Wq, const float* bq,
                            const float* Wk, const float* bk,
                            const float* We, const float* be,
                            const float* Wa, const float* ba,
                            const float* W1, const float* b1,
                            const float* W2, const float* b2,
                            const float* Wo, const float* bo,
                            float* ws, float* out, int nc, hipStream_t stream) {
  const int RPC = ROWS / nc;          // rows per chunk
  const int BPC = BATCH / nc;         // batch elems per chunk
  bf16* attn = (bf16*)((char*)ws + (size_t)PREP_FLOATS * 4);
  bf16* er   = attn + (size_t)RPC * 50;
  bf16* ad   = er   + (size_t)RPC * 200;   // rec overwrites with rd in place

  prep_kernel<<<3645, 256, 0, stream>>>(keymem, Wk, bk, Wv, We, Wa, W1, W2, ws);
  for (int c = 0; c < nc; ++c) {
    int row0 = c * RPC;
    attn_kernel<<<RPC/4,  256, 0, stream>>>(questions, qtab, Wq, bq, ws, attn, row0);
    ea_kernel  <<<RPC/32, 256, 0, stream>>>(questions, responses, bv, be, ba, ws, er, ad, row0);
    rec_kernel <<<dim3(BPC, 4), 64, 0, stream>>>(ivm, attn, er, ad);
    mlp_kernel <<<RPC/64, 512, 0, stream>>>(questions, qtab, b1, b2, Wo, bo, ws, ad, out, row0);
  }
}

extern "C" void kernel_launch(void* const* d_in, const int* in_sizes, int n_in,
                              void* d_out, int out_size, void* d_ws, size_t ws_size,
                              hipStream_t stream) {
  const int*   questions = (const int*)d_in[0];
  const int*   responses = (const int*)d_in[1];
  const float* qtab      = (const float*)d_in[2];
  const float* Wv        = (const float*)d_in[3];
  const float* bv        = (const float*)d_in[4];
  const float* keymem    = (const float*)d_in[5];
  const float* ivm       = (const float*)d_in[6];
  const float* Wq        = (const float*)d_in[7];
  const float* bq        = (const float*)d_in[8];
  const float* Wk        = (const float*)d_in[9];
  const float* bk        = (const float*)d_in[10];
  const float* We        = (const float*)d_in[11];
  const float* be        = (const float*)d_in[12];
  const float* Wa        = (const float*)d_in[13];
  const float* ba        = (const float*)d_in[14];
  const float* W1        = (const float*)d_in[15];
  const float* b1        = (const float*)d_in[16];
  const float* W2        = (const float*)d_in[17];
  const float* b2        = (const float*)d_in[18];
  const float* Wo        = (const float*)d_in[19];
  const float* bo        = (const float*)d_in[20];
  float* ws  = (float*)d_ws;
  float* out = (float*)d_out;

  const size_t prep_b = (size_t)PREP_FLOATS * 4;
  auto need = [&](int nc) {
    return prep_b + ((size_t)ROWS / nc) * 450 * 2;
  };

  int nc;
  if      (ws_size >= need(1))  nc = 1;   // 234 MB: full batch
  else if (ws_size >= need(2))  nc = 2;
  else if (ws_size >= need(4))  nc = 4;
  else if (ws_size >= need(8))  nc = 8;
  else                          nc = 16;
  launch_pipeline(questions, responses, qtab, Wv, bv, keymem, ivm,
                  Wq, bq, Wk, bk, We, be, Wa, ba, W1, b1, W2, b2,
                  Wo, bo, ws, out, nc, stream);
}

// Round 11
// 1898.063 us; speedup vs baseline: 1.9043x; 1.0235x over previous
//
#include <hip/hip_runtime.h>
#include <hip/hip_bf16.h>
#include <math.h>

// Problem constants
#define ROWS 256000     // B*S = 512*500
#define BATCH 512

// prep region (float offsets in ws)
#define OFF_TK   0          // tk [50][50] f32
#define OFF_WVT  2512       // WvT [4000][200] f32
#define OFF_WTB  802512     // WTB bf16 [448 cols][224 k]  (We.T|Wa.T, zero-padded)
#define OFF_W1T  882512     // W1T [250][128] f32 (zero-padded u>=100)
#define OFF_W2T  914512     // W2T [100][52]  f32 (zero-padded f>=50)
#define PREP_FLOATS 919712

// output layout (float offsets)
#define OUT_MAST 12800000
#define OUT_LOG  13056000
#define OUT_PROB 14080000

typedef __hip_bfloat16 bf16;
typedef __attribute__((ext_vector_type(8))) short bf16x8;
typedef __attribute__((ext_vector_type(4))) float f32x4;
__device__ inline float ldT(const bf16* p) { return __bfloat162float(*p); }
__device__ inline void stT(bf16* p, float v) { *p = __float2bfloat16(v); }
__device__ inline short bfbits(float v) { __hip_bfloat16 h = __float2bfloat16(v); return *(short*)&h; }

// ---------------------------------------------------------------- prep ----
__global__ __launch_bounds__(256) void prep_kernel(
    const float* __restrict__ keymem, const float* __restrict__ Wk,
    const float* __restrict__ bk, const float* __restrict__ Wv,
    const float* __restrict__ We, const float* __restrict__ Wa,
    const float* __restrict__ W1, const float* __restrict__ W2,
    float* __restrict__ ws) {
  int idx = blockIdx.x * 256 + threadIdx.x;
  if (idx < 2500) {                      // tk[m][k] = sum_l km[l][k]*Wk[m][l] + bk[m]
    int m = idx / 50, k = idx - m * 50;
    float acc = bk[m];
    for (int l = 0; l < 50; ++l) acc = fmaf(keymem[l*50 + k], Wk[m*50 + l], acc);
    ws[OFF_TK + m*50 + k] = acc;
    return;
  }
  idx -= 2500;
  if (idx < 800000) {                    // WvT[j][v] = Wv[v][j]
    int j = idx / 200, v = idx - j * 200;
    ws[OFF_WVT + j*200 + v] = Wv[v*4000 + j];
    return;
  }
  idx -= 800000;
  if (idx < 100352) {                    // WTB bf16 [448][224]
    int col = idx / 224, k = idx - col * 224;
    float val = 0.f;
    if (k < 200 && col < 400)
      val = (col < 200) ? We[col*200 + k] : Wa[(col-200)*200 + k];
    ((bf16*)(ws + OFF_WTB))[idx] = __float2bfloat16(val);
    return;
  }
  idx -= 100352;
  if (idx < 32000) {                     // W1T[j][u], [250][128]
    int j = idx / 128, u = idx - j * 128;
    ws[OFF_W1T + j*128 + u] = (u < 100) ? W1[u*250 + j] : 0.f;
    return;
  }
  idx -= 32000;
  if (idx < 5200) {                      // W2T[j][f], [100][52]
    int j = idx / 52, f = idx - j * 52;
    ws[OFF_W2T + j*52 + f] = (f < 50) ? W2[f*100 + j] : 0.f;
    return;
  }
}

// ---------------------------------------------------------------- attn ----
// wave per (b,t) row; 4 waves per block; attn buffer is chunk-local
__global__ __launch_bounds__(256) void attn_kernel(
    const int* __restrict__ questions, const float* __restrict__ qtab,
    const float* __restrict__ Wq, const float* __restrict__ bq,
    const float* __restrict__ ws, bf16* __restrict__ attn, int row0) {
  __shared__ float qe_s[4][52];
  __shared__ float qu_s[4][52];
  int w = threadIdx.x >> 6;
  int lane = threadIdx.x & 63;
  int lrow = blockIdx.x * 4 + w;
  int row = row0 + lrow;
  int qi = questions[row];
  if (lane < 50) qe_s[w][lane] = qtab[qi*50 + lane];
  __syncthreads();
  if (lane < 50) {
    float acc = bq[lane];
    const float* wq = Wq + lane*50;
    #pragma unroll
    for (int j = 0; j < 50; ++j) acc = fmaf(qe_s[w][j], wq[j], acc);
    qu_s[w][lane] = tanhf(acc);
  }
  __syncthreads();
  float sc = -3.0e38f;
  if (lane < 50) {
    float acc = 0.f;
    const float* tkr = ws + OFF_TK + lane*50;
    #pragma unroll
    for (int k = 0; k < 50; ++k) acc = fmaf(qu_s[w][k], tkr[k], acc);
    sc = acc;
  }
  float mx = sc;
  #pragma unroll
  for (int d = 32; d > 0; d >>= 1) mx = fmaxf(mx, __shfl_xor(mx, d));
  float ex = (lane < 50) ? __expf(sc - mx) : 0.f;
  float sm = ex;
  #pragma unroll
  for (int d = 32; d > 0; d >>= 1) sm += __shfl_xor(sm, d);
  if (lane < 50) stT(&attn[lrow*50 + lane], ex / sm);
}

// ------------------------------------------------------------ erase/add ----
// MFMA: per block 32 rows; Z[32 x 448] = VE[32 x 224] @ WTB^T
// 512 threads = 8 waves: rw = wid&1 (16-row tile), cw = wid>>1 (112-col strip
// = 7 tiles). acc[7]+breg[7] = 56 VGPR -> batch survives regalloc (cap 128).
__global__ __launch_bounds__(512, 4) void ea_kernel(
    const int* __restrict__ questions, const int* __restrict__ responses,
    const float* __restrict__ bv, const float* __restrict__ be,
    const float* __restrict__ ba, const float* __restrict__ ws,
    bf16* __restrict__ er, bf16* __restrict__ ad, int row0) {
  __shared__ __align__(16) short smem[32*420];   // gather view [32][232], out view [32][420]
  const int tid = threadIdx.x;
  const int lrow0 = blockIdx.x * 32;
  const float* wvt = ws + OFF_WVT;
  const short* wtb = (const short*)(ws + OFF_WTB);

  // ---- gather VE into LDS bf16 [32][232] (k >= 200 zeroed) ----
  for (int i = tid; i < 32*232; i += 512) {
    int r = i / 232, v = i - r*232;
    float acc = 0.f;
    if (v < 200) {
      int row = row0 + lrow0 + r;
      int qi = questions[row];
      acc = bv[v];
      if (qi > 0) {
        int resp = responses[row];
        const float* base = wvt + (qi - 1)*200 + v;
        #pragma unroll
        for (int c = 0; c < 4; ++c) {
          float wgt = 1.f - fabsf((float)(c - resp)) * (1.f/3.f);
          if (wgt > 0.f) acc = fmaf(wgt, base[c*200000], acc);
        }
      }
    }
    smem[r*232 + v] = bfbits(acc);
  }
  __syncthreads();

  // ---- MFMA GEMM: 7 ks x (7 batched B-loads + 1 A ds_read + 7 MFMA) ----
  const int lane = tid & 63, wid = tid >> 6;
  const int rw = wid & 1, cw = wid >> 1;          // cw in [0,4)
  const int arow = rw*16 + (lane & 15);
  const int kb = (lane >> 4) * 8;
  f32x4 acc[7];
  #pragma unroll
  for (int t = 0; t < 7; ++t) acc[t] = (f32x4){0.f, 0.f, 0.f, 0.f};
  const short* bbase = wtb + (size_t)(cw*112 + (lane & 15))*224 + kb;
  const short* abase = &smem[arow*232 + kb];
  #pragma unroll
  for (int ks = 0; ks < 7; ++ks) {
    bf16x8 breg[7];
    #pragma unroll
    for (int t = 0; t < 7; ++t)
      breg[t] = *(const bf16x8*)(bbase + t*(16*224) + ks*32);
    bf16x8 a = *(const bf16x8*)(abase + ks*32);
    #pragma unroll
    for (int t = 0; t < 7; ++t)
      acc[t] = __builtin_amdgcn_mfma_f32_16x16x32_bf16(a, breg[t], acc[t], 0, 0, 0);
  }
  __syncthreads();   // all waves done reading VE before LDS reuse

  // ---- bias + activation, staged to LDS out [32][420] ----
  const int orow = rw*16 + (lane >> 4)*4;
  #pragma unroll
  for (int t = 0; t < 7; ++t) {
    int col = cw*112 + t*16 + (lane & 15);
    if (col < 400) {
      float bias = (col < 200) ? be[col] : ba[col - 200];
      #pragma unroll
      for (int r = 0; r < 4; ++r) {
        float z = acc[t][r] + bias;
        float y = (col < 200) ? 1.f/(1.f + __expf(-z)) : tanhf(z);
        smem[(orow + r)*420 + col] = bfbits(y);
      }
    }
  }
  __syncthreads();

  // ---- coalesced copy out ----
  for (int i = tid; i < 12800; i += 512) {
    int r = i / 400, c = i - r*400;
    short val = smem[r*420 + c];
    if (c < 200) ((short*)er)[(lrow0 + r)*200 + c]         = val;
    else         ((short*)ad)[(lrow0 + r)*200 + (c - 200)] = val;
  }
}

// ------------------------------------------------------------ recurrence ----
// grid = (batch_per_chunk, 4 v-groups); ONE wave per block, no LDS, no barriers.
__device__ inline float lane_bcast(float x, int m) {
  return __uint_as_float(__builtin_amdgcn_readlane(__float_as_uint(x), m));
}

__global__ __launch_bounds__(64) void rec_kernel(
    const float* __restrict__ ivm, const bf16* __restrict__ attn,
    const bf16* __restrict__ er, bf16* __restrict__ ad_rd) {
  const int lane = threadIdx.x;            // 0..63
  const int b    = blockIdx.x;             // chunk-local batch element
  const int vg   = blockIdx.y;             // 0..3
  const int v    = vg * 50 + lane;         // valid if lane<50
  const bool av  = lane < 50;
  const long base = (long)b * 500;

  float vm[50];
  #pragma unroll
  for (int m = 0; m < 50; ++m) vm[m] = 0.f;
  if (av) {
    #pragma unroll
    for (int m = 0; m < 50; ++m) vm[m] = ivm[m*200 + v];
  }

  const bf16* erp = er    + base*200 + v;
  bf16*       adp = ad_rd + base*200 + v;
  const bf16* atp = attn  + base*50  + lane;

  float eb[4], ab[4], tb[4];
  #pragma unroll
  for (int j = 0; j < 4; ++j) { eb[j] = 0.f; ab[j] = 0.f; tb[j] = 0.f; }
  if (av) {
    #pragma unroll
    for (int j = 0; j < 3; ++j) {
      eb[j] = ldT(erp + j*200);
      ab[j] = ldT(adp + j*200);
      tb[j] = ldT(atp + j*50);
    }
  }

  for (int t4 = 0; t4 < 124; ++t4) {
    #pragma unroll
    for (int j = 0; j < 4; ++j) {
      const int t  = t4*4 + j;
      const int cs = j;
      const int ls = (j + 3) & 3;
      if (av) {
        eb[ls] = ldT(erp + (t+3)*200);
        ab[ls] = ldT(adp + (t+3)*200);
        tb[ls] = ldT(atp + (t+3)*50);
      }
      float e0 = eb[cs], a0 = ab[cs], t0 = tb[cs];
      float r0 = 0.f, r1 = 0.f, r2 = 0.f, r3 = 0.f;
      #pragma unroll
      for (int m = 0; m < 48; m += 4) {
        float am0 = lane_bcast(t0, m);
        r0 = fmaf(am0, vm[m], r0);
        vm[m] = fmaf(am0, fmaf(-vm[m], e0, a0), vm[m]);
        float am1 = lane_bcast(t0, m + 1);
        r1 = fmaf(am1, vm[m+1], r1);
        vm[m+1] = fmaf(am1, fmaf(-vm[m+1], e0, a0), vm[m+1]);
        float am2 = lane_bcast(t0, m + 2);
        r2 = fmaf(am2, vm[m+2], r2);
        vm[m+2] = fmaf(am2, fmaf(-vm[m+2], e0, a0), vm[m+2]);
        float am3 = lane_bcast(t0, m + 3);
        r3 = fmaf(am3, vm[m+3], r3);
        vm[m+3] = fmaf(am3, fmaf(-vm[m+3], e0, a0), vm[m+3]);
      }
      {
        float am0 = lane_bcast(t0, 48);
        r0 = fmaf(am0, vm[48], r0);
        vm[48] = fmaf(am0, fmaf(-vm[48], e0, a0), vm[48]);
        float am1 = lane_bcast(t0, 49);
        r1 = fmaf(am1, vm[49], r1);
        vm[49] = fmaf(am1, fmaf(-vm[49], e0, a0), vm[49]);
      }
      if (av) stT(adp + t*200, (r0 + r1) + (r2 + r3));
    }
  }
  #pragma unroll
  for (int j = 0; j < 4; ++j) {
    const int t  = 496 + j;
    const int cs = j;
    const int ls = (j + 3) & 3;
    if (j == 0 && av) {
      eb[ls] = ldT(erp + 499*200);
      ab[ls] = ldT(adp + 499*200);
      tb[ls] = ldT(atp + 499*50);
    }
    float e0 = eb[cs], a0 = ab[cs], t0 = tb[cs];
    float r0 = 0.f, r1 = 0.f, r2 = 0.f, r3 = 0.f;
    #pragma unroll
    for (int m = 0; m < 48; m += 4) {
      float am0 = lane_bcast(t0, m);
      r0 = fmaf(am0, vm[m], r0);
      vm[m] = fmaf(am0, fmaf(-vm[m], e0, a0), vm[m]);
      float am1 = lane_bcast(t0, m + 1);
      r1 = fmaf(am1, vm[m+1], r1);
      vm[m+1] = fmaf(am1, fmaf(-vm[m+1], e0, a0), vm[m+1]);
      float am2 = lane_bcast(t0, m + 2);
      r2 = fmaf(am2, vm[m+2], r2);
      vm[m+2] = fmaf(am2, fmaf(-vm[m+2], e0, a0), vm[m+2]);
      float am3 = lane_bcast(t0, m + 3);
      r3 = fmaf(am3, vm[m+3], r3);
      vm[m+3] = fmaf(am3, fmaf(-vm[m+3], e0, a0), vm[m+3]);
    }
    {
      float am0 = lane_bcast(t0, 48);
      r0 = fmaf(am0, vm[48], r0);
      vm[48] = fmaf(am0, fmaf(-vm[48], e0, a0), vm[48]);
      float am1 = lane_bcast(t0, 49);
      r1 = fmaf(am1, vm[49], r1);
      vm[49] = fmaf(am1, fmaf(-vm[49], e0, a0), vm[49]);
    }
    if (av) stT(adp + t*200, (r0 + r1) + (r2 + r3));
  }
}

// ---------------------------------------------------------------- MLP ----
// 64 rows/block, 512 threads; GEMM1 [64x128] K=250 (4x4 reg tile), GEMM2 [64x52] K=100
#define W1S 0
#define HS  6400
#define Z1S 0
#define W2S 6656
#define FTS 11856

__global__ __launch_bounds__(512) void mlp_kernel(
    const int* __restrict__ questions, const float* __restrict__ qtab,
    const float* __restrict__ b1, const float* __restrict__ b2,
    const float* __restrict__ Wo, const float* __restrict__ bo,
    const float* __restrict__ ws, const bf16* __restrict__ rd,
    float* __restrict__ out, int row0) {
  __shared__ __align__(16) float smem[15184];
  int tid = threadIdx.x;
  int lrow0 = blockIdx.x * 64;
  const float* w1t = ws + OFF_W1T;
  int ug = tid & 31, rg = tid >> 5;
  int u0 = ug * 4, r0 = rg * 4;
  float acc[4][4];
  #pragma unroll
  for (int i = 0; i < 4; ++i)
    #pragma unroll
    for (int j = 0; j < 4; ++j) acc[i][j] = 0.f;

  for (int kt = 0; kt < 5; ++kt) {
    int j0 = kt * 50;
    for (int i = tid; i < 6400; i += 512)        // W1T tile [50][128]
      smem[W1S + i] = w1t[j0*128 + i];
    for (int i = tid; i < 3200; i += 512) {      // h tile [64][50]
      int r = i / 50, jj = i - r * 50;
      int lrow = lrow0 + r;
      int j = j0 + jj;
      float hv;
      if (j < 200) hv = ldT(&rd[lrow*200 + j]);
      else         hv = qtab[questions[row0 + lrow]*50 + (j - 200)];
      smem[HS + r*50 + jj] = hv;
    }
    __syncthreads();
    #pragma unroll 2
    for (int jj = 0; jj < 50; ++jj) {
      float4 wv = *(const float4*)&smem[W1S + jj*128 + u0];
      #pragma unroll
      for (int rr = 0; rr < 4; ++rr) {
        float h = smem[HS + (r0 + rr)*50 + jj];
        acc[rr][0] = fmaf(h, wv.x, acc[rr][0]);
        acc[rr][1] = fmaf(h, wv.y, acc[rr][1]);
        acc[rr][2] = fmaf(h, wv.z, acc[rr][2]);
        acc[rr][3] = fmaf(h, wv.w, acc[rr][3]);
      }
    }
    __syncthreads();
  }
  // z1 = relu(acc + b1) into LDS [64][104]
  if (u0 < 100) {
    #pragma unroll
    for (int uu = 0; uu < 4; ++uu) {
      int u = u0 + uu;
      float bb = b1[u];
      #pragma unroll
      for (int rr = 0; rr < 4; ++rr) {
        float z = acc[rr][uu] + bb;
        smem[Z1S + (r0 + rr)*104 + u] = fmaxf(z, 0.f);
      }
    }
  }
  for (int i = tid; i < 5200; i += 512)          // W2T [100][52]
    smem[W2S + i] = ws[OFF_W2T + i];
  __syncthreads();
  // GEMM2: feat [64][50]
  for (int i = tid; i < 832; i += 512) {
    int r = i / 13, fg = i - r * 13;
    int f0 = fg * 4;
    float a0 = 0.f, a1 = 0.f, a2 = 0.f, a3 = 0.f;
    #pragma unroll 4
    for (int j = 0; j < 100; ++j) {
      float z = smem[Z1S + r*104 + j];
      float4 wv = *(const float4*)&smem[W2S + j*52 + f0];
      a0 = fmaf(z, wv.x, a0);
      a1 = fmaf(z, wv.y, a1);
      a2 = fmaf(z, wv.z, a2);
      a3 = fmaf(z, wv.w, a3);
    }
    int row = row0 + lrow0 + r;
    float vals[4] = {a0, a1, a2, a3};
    #pragma unroll
    for (int ff = 0; ff < 4; ++ff) {
      int f = f0 + ff;
      if (f < 50) {
        float val = vals[ff] + b2[f];
        smem[FTS + r*52 + f] = val;
        out[row*50 + f] = val;
      }
    }
  }
  __syncthreads();
  // mastery / logits / probs
  if (tid < 64) {
    int r = tid, row = row0 + lrow0 + r;
    float s = 0.f;
    float lg[4] = {bo[0], bo[1], bo[2], bo[3]};
    #pragma unroll
    for (int f = 0; f < 50; ++f) {
      float ft = smem[FTS + r*52 + f];
      s += ft;
      #pragma unroll
      for (int c = 0; c < 4; ++c) lg[c] = fmaf(Wo[c*50 + f], ft, lg[c]);
    }
    out[OUT_MAST + row] = s * (1.f / 50.f);
    float mx = fmaxf(fmaxf(lg[0], lg[1]), fmaxf(lg[2], lg[3]));
    float e0 = __expf(lg[0] - mx), e1 = __expf(lg[1] - mx);
    float e2 = __expf(lg[2] - mx), e3 = __expf(lg[3] - mx);
    float inv = 1.f / (e0 + e1 + e2 + e3);
    #pragma unroll
    for (int c = 0; c < 4; ++c) out[OUT_LOG + row*4 + c] = lg[c];
    out[OUT_PROB + row*4 + 0] = e0 * inv;
    out[OUT_PROB + row*4 + 1] = e1 * inv;
    out[OUT_PROB + row*4 + 2] = e2 * inv;
    out[OUT_PROB + row*4 + 3] = e3 * inv;
  }
}

// ---------------------------------------------------------------- launch ----
static void launch_pipeline(const int* questions, const int* responses,
                            const float* qtab, const float* Wv, const float* bv,
                            const float* keymem, const float* ivm,
                            const float* Wq, const float* bq,
                            const float* Wk, const float* bk,
                            const float* We, const float* be,
                            const float* Wa, const float* ba,
                            const float* W1, const float* b1,
                            const float* W2, const float* b2,
                            const float* Wo, const float* bo,
                            float* ws, float* out, int nc, hipStream_t stream) {
  const int RPC = ROWS / nc;          // rows per chunk
  const int BPC = BATCH / nc;         // batch elems per chunk
  bf16* attn = (bf16*)((char*)ws + (size_t)PREP_FLOATS * 4);
  bf16* er   = attn + (size_t)RPC * 50;
  bf16* ad   = er   + (size_t)RPC * 200;   // rec overwrites with rd in place

  prep_kernel<<<3673, 256, 0, stream>>>(keymem, Wk, bk, Wv, We, Wa, W1, W2, ws);
  for (int c = 0; c < nc; ++c) {
    int row0 = c * RPC;
    attn_kernel<<<RPC/4,  256, 0, stream>>>(questions, qtab, Wq, bq, ws, attn, row0);
    ea_kernel  <<<RPC/32, 512, 0, stream>>>(questions, responses, bv, be, ba, ws, er, ad, row0);
    rec_kernel <<<dim3(BPC, 4), 64, 0, stream>>>(ivm, attn, er, ad);
    mlp_kernel <<<RPC/64, 512, 0, stream>>>(questions, qtab, b1, b2, Wo, bo, ws, ad, out, row0);
  }
}

extern "C" void kernel_launch(void* const* d_in, const int* in_sizes, int n_in,
                              void* d_out, int out_size, void* d_ws, size_t ws_size,
                              hipStream_t stream) {
  const int*   questions = (const int*)d_in[0];
  const int*   responses = (const int*)d_in[1];
  const float* qtab      = (const float*)d_in[2];
  const float* Wv        = (const float*)d_in[3];
  const float* bv        = (const float*)d_in[4];
  const float* keymem    = (const float*)d_in[5];
  const float* ivm       = (const float*)d_in[6];
  const float* Wq        = (const float*)d_in[7];
  const float* bq        = (const float*)d_in[8];
  const float* Wk        = (const float*)d_in[9];
  const float* bk        = (const float*)d_in[10];
  const float* We        = (const float*)d_in[11];
  const float* be        = (const float*)d_in[12];
  const float* Wa        = (const float*)d_in[13];
  const float* ba        = (const float*)d_in[14];
  const float* W1        = (const float*)d_in[15];
  const float* b1        = (const float*)d_in[16];
  const float* W2        = (const float*)d_in[17];
  const float* b2        = (const float*)d_in[18];
  const float* Wo        = (const float*)d_in[19];
  const float* bo        = (const float*)d_in[20];
  float* ws  = (float*)d_ws;
  float* out = (float*)d_out;

  const size_t prep_b = (size_t)PREP_FLOATS * 4;
  auto need = [&](int nc) {
    return prep_b + ((size_t)ROWS / nc) * 450 * 2;
  };

  int nc;
  if      (ws_size >= need(1))  nc = 1;   // 234 MB: full batch
  else if (ws_size >= need(2))  nc = 2;
  else if (ws_size >= need(4))  nc = 4;
  else if (ws_size >= need(8))  nc = 8;
  else                          nc = 16;
  launch_pipeline(questions, responses, qtab, Wv, bv, keymem, ivm,
                  Wq, bq, Wk, bk, We, be, Wa, ba, W1, b1, W2, b2,
                  Wo, bo, ws, out, nc, stream);
}